// Round 2
// baseline (3230.614 us; speedup 1.0000x reference)
//
#include <hip/hip_runtime.h>

// Problem constants
constexpr int cB = 32, cN = 512, cC = 64, cT = 24, cK = 3, cF = 64;
constexpr int cCT = cC * cT;   // 1536
constexpr int cFT = cF * cT;   // 1536

// ---------------------------------------------------------------------------
// lhs[b,n,t2] = sum_c (sum_t x[b,n,c,t]*W1[t]) * W2[c,t2]
// rhs[b,n,t]  = sum_c x[b,n,c,t]*W3[c]
__global__ __launch_bounds__(64) void k_spatial_lr(
    const float* __restrict__ x, const float* __restrict__ W1,
    const float* __restrict__ W2, const float* __restrict__ W3,
    float* __restrict__ lhs, float* __restrict__ rhs)
{
    int bn = blockIdx.x;          // b*N+n
    int tid = threadIdx.x;        // 0..63
    __shared__ float xs[64][25];  // padded
    __shared__ float a_sh[64];
    const float* xp = x + (size_t)bn * cCT;
    for (int i = tid; i < cCT; i += 64) xs[i / cT][i % cT] = xp[i];
    __syncthreads();
    float s = 0.f;
    #pragma unroll
    for (int t = 0; t < cT; t++) s += xs[tid][t] * W1[t];
    a_sh[tid] = s;
    __syncthreads();
    if (tid < cT) {
        float l = 0.f, r = 0.f;
        for (int c = 0; c < cC; c++) {
            l += a_sh[c] * W2[c * cT + tid];
            r += xs[c][tid] * W3[c];
        }
        lhs[(size_t)bn * cT + tid] = l;
        rhs[(size_t)bn * cT + tid] = r;
    }
}

// ---------------------------------------------------------------------------
// P[b,m,n] = sigmoid(sum_t lhs[b,m,t]*rhs[b,n,t] + bs[m,n])
__global__ __launch_bounds__(256) void k_product(
    const float* __restrict__ lhs, const float* __restrict__ rhs,
    const float* __restrict__ bs, float* __restrict__ P)
{
    int b = blockIdx.z;
    int m0 = blockIdx.y * 16, n0 = blockIdx.x * 16;
    int tx = threadIdx.x, ty = threadIdx.y;
    int tid = ty * 16 + tx;
    __shared__ float L[16][25], R[16][25];
    for (int i = tid; i < 16 * cT; i += 256) {
        int r = i / cT, c = i % cT;
        L[r][c] = lhs[((size_t)b * cN + m0 + r) * cT + c];
        R[r][c] = rhs[((size_t)b * cN + n0 + r) * cT + c];
    }
    __syncthreads();
    float s = 0.f;
    #pragma unroll
    for (int t = 0; t < cT; t++) s += L[ty][t] * R[tx][t];
    int m = m0 + ty, n = n0 + tx;
    s += bs[(size_t)m * cN + n];
    P[((size_t)b * cN + m) * cN + n] = 1.f / (1.f + expf(-s));
}

// ---------------------------------------------------------------------------
// Generic tiled SGEMM: C[b] (acc?+=:=) A[b] @ B[b], optional ReLU epilogue.
// 64x64 tile, BK=16, 256 threads, 4x4 microtile.
__global__ __launch_bounds__(256) void k_sgemm(
    const float* __restrict__ A, long long aB,
    const float* __restrict__ Bm, long long bB,
    float* __restrict__ Cm, long long cBs,
    int M, int Ncols, int Kd, int doAcc, int doRelu)
{
    __shared__ float As[16][65];  // [k][m], padded
    __shared__ float Bs[16][64];  // [k][n]
    int tid = threadIdx.x;
    int tx = tid % 16, ty = tid / 16;
    int bn = blockIdx.x * 64;
    int bm = blockIdx.y * 64;
    int b  = blockIdx.z;
    const float* Ap = A  + (size_t)b * aB;
    const float* Bp = Bm + (size_t)b * bB;
    float*       Cp = Cm + (size_t)b * cBs;
    float acc[4][4];
    #pragma unroll
    for (int i = 0; i < 4; i++)
        #pragma unroll
        for (int j = 0; j < 4; j++) acc[i][j] = 0.f;
    int ac = tid % 16, ar = tid / 16;   // A: col, row0
    int bni = tid % 64, bki = tid / 64; // B: col, k0
    for (int k0 = 0; k0 < Kd; k0 += 16) {
        #pragma unroll
        for (int i = 0; i < 4; i++)
            As[ac][ar + 16 * i] = Ap[(size_t)(bm + ar + 16 * i) * Kd + k0 + ac];
        #pragma unroll
        for (int i = 0; i < 4; i++)
            Bs[bki + 4 * i][bni] = Bp[(size_t)(k0 + bki + 4 * i) * Ncols + bn + bni];
        __syncthreads();
        #pragma unroll
        for (int kk = 0; kk < 16; kk++) {
            float a[4], bb[4];
            #pragma unroll
            for (int i = 0; i < 4; i++) a[i] = As[kk][ty + 16 * i];
            #pragma unroll
            for (int j = 0; j < 4; j++) bb[j] = Bs[kk][tx + 16 * j];
            #pragma unroll
            for (int i = 0; i < 4; i++)
                #pragma unroll
                for (int j = 0; j < 4; j++) acc[i][j] += a[i] * bb[j];
        }
        __syncthreads();
    }
    #pragma unroll
    for (int i = 0; i < 4; i++) {
        #pragma unroll
        for (int j = 0; j < 4; j++) {
            size_t idx = (size_t)(bm + ty + 16 * i) * Ncols + bn + tx + 16 * j;
            float v = acc[i][j];
            if (doAcc) v += Cp[idx];
            if (doRelu) v = fmaxf(v, 0.f);
            Cp[idx] = v;
        }
    }
}

// ---------------------------------------------------------------------------
// Row softmax over 512 columns, in place.
__global__ __launch_bounds__(256) void k_softmax512(float* __restrict__ S)
{
    int row = blockIdx.x;
    int tid = threadIdx.x;
    float* p = S + (size_t)row * cN;
    float v0 = p[tid], v1 = p[tid + 256];
    __shared__ float red[256];
    red[tid] = fmaxf(v0, v1);
    __syncthreads();
    for (int off = 128; off > 0; off >>= 1) {
        if (tid < off) red[tid] = fmaxf(red[tid], red[tid + off]);
        __syncthreads();
    }
    float mx = red[0];
    __syncthreads();
    float e0 = expf(v0 - mx), e1 = expf(v1 - mx);
    red[tid] = e0 + e1;
    __syncthreads();
    for (int off = 128; off > 0; off >>= 1) {
        if (tid < off) red[tid] += red[tid + off];
        __syncthreads();
    }
    float inv = 1.f / red[0];
    p[tid] = e0 * inv;
    p[tid + 256] = e1 * inv;
}

// ---------------------------------------------------------------------------
// XT[b,n,f,t] = sum_c x[b,n,c,t] * Theta[k,c,f]
__global__ __launch_bounds__(256) void k_xtheta(
    const float* __restrict__ x, const float* __restrict__ Theta, int k,
    float* __restrict__ XT)
{
    int bn = blockIdx.x;
    int tid = threadIdx.x;
    __shared__ float xs[64][25];
    __shared__ float th[64 * 64];
    __shared__ float outs[64 * 25];
    const float* xp = x + (size_t)bn * cCT;
    for (int i = tid; i < cCT; i += 256) xs[i / cT][i % cT] = xp[i];
    const float* tp = Theta + (size_t)k * cC * cF;
    for (int i = tid; i < cC * cF; i += 256) th[i] = tp[i];
    __syncthreads();
    int f = tid & 63, g = tid >> 6;
    #pragma unroll
    for (int j = 0; j < 6; j++) {
        int t = g * 6 + j;
        float s = 0.f;
        #pragma unroll
        for (int c = 0; c < 64; c++) s += xs[c][t] * th[c * 64 + f];
        outs[f * 25 + t] = s;
    }
    __syncthreads();
    float* op = XT + (size_t)bn * cFT;
    for (int i = tid; i < cFT; i += 256) op[i] = outs[(i / cT) * 25 + i % cT];
}

// ---------------------------------------------------------------------------
// partial hU1: part[b,nc,f,t] = sum_{n in chunk} U1[n]*h[b,n,f,t]
__global__ __launch_bounds__(256) void k_hU1_part(
    const float* __restrict__ h, const float* __restrict__ U1,
    float* __restrict__ part)
{
    int b = blockIdx.x, nc = blockIdx.y;
    int tid = threadIdx.x;
    int f = tid & 63, q = tid >> 6;
    float acc[24];
    #pragma unroll
    for (int t = 0; t < 24; t++) acc[t] = 0.f;
    for (int n = nc * 32 + q; n < nc * 32 + 32; n += 4) {
        float u = U1[n];
        const float4* hp = (const float4*)(h + (((size_t)b * cN + n) * cF + f) * cT);
        #pragma unroll
        for (int v4 = 0; v4 < 6; v4++) {
            float4 hv = hp[v4];
            acc[v4 * 4 + 0] += u * hv.x;
            acc[v4 * 4 + 1] += u * hv.y;
            acc[v4 * 4 + 2] += u * hv.z;
            acc[v4 * 4 + 3] += u * hv.w;
        }
    }
    __shared__ float ps[4][64][25];
    #pragma unroll
    for (int t = 0; t < 24; t++) ps[q][f][t] = acc[t];
    __syncthreads();
    for (int i = tid; i < cFT; i += 256) {
        int f2 = i / cT, t2 = i % cT;
        float s = ps[0][f2][t2] + ps[1][f2][t2] + ps[2][f2][t2] + ps[3][f2][t2];
        part[(((size_t)b * 16 + nc) * cF + f2) * cT + t2] = s;
    }
}

// ---------------------------------------------------------------------------
// hU1[b,t,f] = sum_nc part; lhs_t[b,t,nn] = sum_f hU1[b,t,f]*U2[f,nn]
__global__ __launch_bounds__(256) void k_lhs_t(
    const float* __restrict__ part, const float* __restrict__ U2,
    float* __restrict__ lhs_t)
{
    int b = blockIdx.x, ch = blockIdx.y;  // ch: nn chunk of 128
    int tid = threadIdx.x;
    __shared__ float hu[1536];  // [f*24+t]
    for (int i = tid; i < 1536; i += 256) {
        float s = 0.f;
        for (int nc = 0; nc < 16; nc++)
            s += part[((size_t)b * 16 + nc) * 1536 + i];
        hu[i] = s;
    }
    __syncthreads();
    int nn0 = ch * 128;
    for (int i = tid; i < cT * 128; i += 256) {
        int t = i / 128, nn = nn0 + (i % 128);
        float s = 0.f;
        #pragma unroll
        for (int f = 0; f < 64; f++) s += hu[f * cT + t] * U2[(size_t)f * cN + nn];
        lhs_t[((size_t)b * cT + t) * cN + nn] = s;
    }
}

// ---------------------------------------------------------------------------
// rhs_t[b,n,t] = sum_f U3[f]*h[b,n,f,t]
__global__ __launch_bounds__(64) void k_rhs_t(
    const float* __restrict__ h, const float* __restrict__ U3,
    float* __restrict__ rhs_t)
{
    int bn = blockIdx.x;
    int f = threadIdx.x;
    __shared__ float sl[64][25];
    const float4* hp = (const float4*)(h + (size_t)bn * cFT + f * cT);
    float u = U3[f];
    #pragma unroll
    for (int v4 = 0; v4 < 6; v4++) {
        float4 hv = hp[v4];
        sl[f][v4 * 4 + 0] = u * hv.x;
        sl[f][v4 * 4 + 1] = u * hv.y;
        sl[f][v4 * 4 + 2] = u * hv.z;
        sl[f][v4 * 4 + 3] = u * hv.w;
    }
    __syncthreads();
    if (f < cT) {
        float s = 0.f;
        #pragma unroll
        for (int c = 0; c < 64; c++) s += sl[c][f];
        rhs_t[(size_t)bn * cT + f] = s;
    }
}

// ---------------------------------------------------------------------------
// E[b,t,r] = softmax_r( sum_s Ve[t,s]*sigmoid(prod_t[b,s,r]+be[s,r]) )
// prod_t[b,t,s] = sum_n lhs_t[b,t,n]*rhs_t[b,n,s]
__global__ __launch_bounds__(576) void k_E(
    const float* __restrict__ lhs_t, const float* __restrict__ rhs_t,
    const float* __restrict__ be, const float* __restrict__ Ve,
    float* __restrict__ E)
{
    int b = blockIdx.x;
    int tid = threadIdx.x;
    int i = tid / 24, j = tid % 24;
    __shared__ float ps[24][25];
    __shared__ float er[24][25];
    __shared__ float mrow[24], srow[24];
    const float* lp = lhs_t + ((size_t)b * cT + i) * cN;
    const float* rp = rhs_t + (size_t)b * cN * cT;
    float s = 0.f;
    for (int n = 0; n < cN; n++) s += lp[n] * rp[n * cT + j];
    s += be[i * cT + j];
    ps[i][j] = 1.f / (1.f + expf(-s));
    __syncthreads();
    float e = 0.f;
    #pragma unroll
    for (int ss = 0; ss < cT; ss++) e += Ve[i * cT + ss] * ps[ss][j];
    er[i][j] = e;
    __syncthreads();
    if (j == 0) {
        float m = -1e30f;
        for (int r = 0; r < cT; r++) m = fmaxf(m, er[i][r]);
        float sm = 0.f;
        for (int r = 0; r < cT; r++) sm += expf(er[i][r] - m);
        mrow[i] = m;
        srow[i] = sm;
    }
    __syncthreads();
    E[(size_t)b * cT * cT + i * cT + j] = expf(er[i][j] - mrow[i]) / srow[i];
}

// ---------------------------------------------------------------------------
// h[b,n,f,s] = sum_t h[b,n,f,t]*E[b,t,s]   (in place per (b,n) slab)
__global__ __launch_bounds__(256) void k_tmix(float* __restrict__ h,
                                              const float* __restrict__ E)
{
    int bn = blockIdx.x;
    int b = bn >> 9;
    int tid = threadIdx.x;
    __shared__ float hs[64][25];
    __shared__ float Es[24][24];
    __shared__ float outs[64 * 25];
    float* hp = h + (size_t)bn * cFT;
    for (int i = tid; i < cFT; i += 256) hs[i / cT][i % cT] = hp[i];
    for (int i = tid; i < 576; i += 256)              // FIX: was `if (tid<576)` with 256 threads
        Es[i / 24][i % 24] = E[(size_t)b * 576 + i];
    __syncthreads();
    int f = tid & 63, g = tid >> 6;
    #pragma unroll
    for (int j = 0; j < 6; j++) {
        int so = g * 6 + j;
        float s = 0.f;
        #pragma unroll
        for (int t = 0; t < cT; t++) s += hs[f][t] * Es[t][so];
        outs[f * 25 + so] = s;
    }
    __syncthreads();
    for (int i = tid; i < cFT; i += 256) hp[i] = outs[(i / cT) * 25 + i % cT];
}

// ---------------------------------------------------------------------------
// conv(1,3) over T + bias + residual(x) + LayerNorm over F. In place on h.
__global__ __launch_bounds__(256) void k_convln(
    float* __restrict__ h, const float* __restrict__ x,
    const float* __restrict__ cw, const float* __restrict__ cb,
    const float* __restrict__ lnw, const float* __restrict__ lnb)
{
    int bn = blockIdx.x;
    int tid = threadIdx.x;
    int f = tid & 63, g = tid >> 6;
    __shared__ float hs[64][26];       // halo-padded in t
    __shared__ float wT[64 * 64 * 3];  // [fi][f][d]
    __shared__ float xs2[64 * 25];
    __shared__ float outs[64 * 25];
    float* hp = h + (size_t)bn * cFT;
    for (int i = tid; i < cFT; i += 256) hs[i / cT][1 + i % cT] = hp[i];
    if (tid < 64) { hs[tid][0] = 0.f; hs[tid][25] = 0.f; }
    const float* xp = x + (size_t)bn * cCT;
    for (int i = tid; i < cCT; i += 256) xs2[(i / cT) * 25 + i % cT] = xp[i];
    for (int i = tid; i < 64 * 64 * 3; i += 256) {
        int ff = i / 192, rest = i % 192;
        int fi = rest / 3, d = rest % 3;
        wT[(fi * 64 + ff) * 3 + d] = cw[i];
    }
    __syncthreads();
    float acc[6];
    float bias = cb[f];
    #pragma unroll
    for (int j = 0; j < 6; j++) acc[j] = bias;
    for (int fi = 0; fi < 64; fi++) {
        float r[8];
        #pragma unroll
        for (int c = 0; c < 8; c++) r[c] = hs[fi][g * 6 + c];
        float w0 = wT[(fi * 64 + f) * 3 + 0];
        float w1 = wT[(fi * 64 + f) * 3 + 1];
        float w2 = wT[(fi * 64 + f) * 3 + 2];
        #pragma unroll
        for (int j = 0; j < 6; j++) acc[j] += w0 * r[j] + w1 * r[j + 1] + w2 * r[j + 2];
    }
    float w_ln = lnw[f], b_ln = lnb[f];
    #pragma unroll
    for (int j = 0; j < 6; j++) {
        int t = g * 6 + j;
        float v = acc[j] + xs2[f * 25 + t];
        float s1 = v, s2 = v * v;
        #pragma unroll
        for (int off = 1; off < 64; off <<= 1) {
            s1 += __shfl_xor(s1, off, 64);
            s2 += __shfl_xor(s2, off, 64);
        }
        float mean = s1 * (1.f / 64.f);
        float var = s2 * (1.f / 64.f) - mean * mean;
        float rstd = rsqrtf(var + 1e-5f);
        outs[f * 25 + t] = (v - mean) * rstd * w_ln + b_ln;
    }
    __syncthreads();
    for (int i = tid; i < cFT; i += 256) hp[i] = outs[(i / cT) * 25 + i % cT];
}

// ---------------------------------------------------------------------------
extern "C" void kernel_launch(void* const* d_in, const int* in_sizes, int n_in,
                              void* d_out, int out_size, void* d_ws, size_t ws_size,
                              hipStream_t stream)
{
    const float* x     = (const float*)d_in[0];
    const float* cheb  = (const float*)d_in[1];
    const float* W1    = (const float*)d_in[2];
    const float* W2    = (const float*)d_in[3];
    const float* W3    = (const float*)d_in[4];
    const float* bs    = (const float*)d_in[5];
    const float* Vs    = (const float*)d_in[6];
    const float* U1    = (const float*)d_in[7];
    const float* U2    = (const float*)d_in[8];
    const float* U3    = (const float*)d_in[9];
    const float* be    = (const float*)d_in[10];
    const float* Ve    = (const float*)d_in[11];
    const float* Theta = (const float*)d_in[12];
    const float* cw    = (const float*)d_in[13];
    const float* cbp   = (const float*)d_in[14];
    const float* lnw   = (const float*)d_in[15];
    const float* lnb   = (const float*)d_in[16];
    float* out = (float*)d_out;
    float* ws  = (float*)d_ws;

    // workspace layout (floats). P region is reused: P -> W -> part/E.
    float* P    = ws;                  // 8,388,608  (B*N*N)
    float* S    = ws + 8388608;        // 8,388,608
    float* XT   = ws + 16777216;       // 25,165,824 (B*N*F*T)
    float* lhs  = ws + 41943040;       // 393,216    (later lhs_t)
    float* rhs  = ws + 42336256;       // 393,216    (later rhs_t)
    float* W    = P;                   // alias (P dead after S gemm)
    float* part = P;                   // alias (W dead after k-loop)
    float* Ebuf = P + 786432;          // after part region

    const long long NN2 = (long long)cN * cN;        // 262144
    const long long NFT = (long long)cN * cFT;       // 786432

    k_spatial_lr<<<cB * cN, 64, 0, stream>>>(x, W1, W2, W3, lhs, rhs);
    k_product<<<dim3(32, 32, cB), dim3(16, 16), 0, stream>>>(lhs, rhs, bs, P);
    // S_raw = Vs @ P  (A shared)
    k_sgemm<<<dim3(8, 8, cB), 256, 0, stream>>>(Vs, 0LL, P, NN2, S, NN2,
                                                cN, cN, cN, 0, 0);
    k_softmax512<<<cB * cN, 256, 0, stream>>>(S);

    for (int k = 0; k < cK; k++) {
        k_xtheta<<<cB * cN, 256, 0, stream>>>(x, Theta, k, XT);
        // W = cheb_k @ S  (A shared)
        k_sgemm<<<dim3(8, 8, cB), 256, 0, stream>>>(cheb + (size_t)k * NN2, 0LL,
                                                    S, NN2, W, NN2,
                                                    cN, cN, cN, 0, 0);
        // h (+)= W @ XT ; relu on last k
        k_sgemm<<<dim3(24, 8, cB), 256, 0, stream>>>(W, NN2, XT, NFT, out, NFT,
                                                     cN, cFT, cN,
                                                     (k > 0) ? 1 : 0,
                                                     (k == 2) ? 1 : 0);
    }

    // temporal attention (uses h = out, pre-mixing)
    k_hU1_part<<<dim3(cB, 16), 256, 0, stream>>>(out, U1, part);
    k_rhs_t<<<cB * cN, 64, 0, stream>>>(out, U3, rhs);
    k_lhs_t<<<dim3(cB, 4), 256, 0, stream>>>(part, U2, lhs);
    k_E<<<cB, 576, 0, stream>>>(lhs, rhs, be, Ve, Ebuf);
    k_tmix<<<cB * cN, 256, 0, stream>>>(out, Ebuf);
    k_convln<<<cB * cN, 256, 0, stream>>>(out, x, cw, cbp, lnw, lnb);
}

// Round 3
// 1883.446 us; speedup vs baseline: 1.7153x; 1.7153x over previous
//
#include <hip/hip_runtime.h>

// Problem constants
constexpr int cB = 32, cN = 512, cC = 64, cT = 24, cK = 3, cF = 64;
constexpr int cCT = cC * cT;   // 1536
constexpr int cFT = cF * cT;   // 1536

typedef __attribute__((ext_vector_type(8))) short s16x8;            // MFMA bf16 frag (8 bf16)
typedef __attribute__((ext_vector_type(8))) unsigned short u16x8;   // 16B load/store
typedef __attribute__((ext_vector_type(4))) float f32x4;            // MFMA acc

__device__ inline unsigned short f2bf(float f) {
    union { float f; unsigned int u; } v; v.f = f;
    unsigned int r = v.u + 0x7FFFu + ((v.u >> 16) & 1u);
    return (unsigned short)(r >> 16);
}

// ---------------------------------------------------------------------------
// lhs[b,n,t2] = sum_c (sum_t x[b,n,c,t]*W1[t]) * W2[c,t2]
// rhs[b,n,t]  = sum_c x[b,n,c,t]*W3[c]
__global__ __launch_bounds__(64) void k_spatial_lr(
    const float* __restrict__ x, const float* __restrict__ W1,
    const float* __restrict__ W2, const float* __restrict__ W3,
    float* __restrict__ lhs, float* __restrict__ rhs)
{
    int bn = blockIdx.x;
    int tid = threadIdx.x;
    __shared__ float xs[64][25];
    __shared__ float a_sh[64];
    const float* xp = x + (size_t)bn * cCT;
    for (int i = tid; i < cCT; i += 64) xs[i / cT][i % cT] = xp[i];
    __syncthreads();
    float s = 0.f;
    #pragma unroll
    for (int t = 0; t < cT; t++) s += xs[tid][t] * W1[t];
    a_sh[tid] = s;
    __syncthreads();
    if (tid < cT) {
        float l = 0.f, r = 0.f;
        for (int c = 0; c < cC; c++) {
            l += a_sh[c] * W2[c * cT + tid];
            r += xs[c][tid] * W3[c];
        }
        lhs[(size_t)bn * cT + tid] = l;
        rhs[(size_t)bn * cT + tid] = r;
    }
}

// ---------------------------------------------------------------------------
// Pt[b,n,m] = bf16(sigmoid(sum_t lhs[b,m,t]*rhs[b,n,t] + bs[m,n]))  (transposed!)
__global__ __launch_bounds__(256) void k_product_t(
    const float* __restrict__ lhs, const float* __restrict__ rhs,
    const float* __restrict__ bs, unsigned short* __restrict__ Pt)
{
    int b = blockIdx.z;
    int m0 = blockIdx.y * 16, n0 = blockIdx.x * 16;
    int tx = threadIdx.x, ty = threadIdx.y;
    int tid = ty * 16 + tx;
    __shared__ float L[16][25], R[16][25], bss[16][17];
    for (int i = tid; i < 16 * cT; i += 256) {
        int r = i / cT, c = i % cT;
        L[r][c] = lhs[((size_t)b * cN + m0 + r) * cT + c];
        R[r][c] = rhs[((size_t)b * cN + n0 + r) * cT + c];
    }
    bss[tid >> 4][tid & 15] = bs[(size_t)(m0 + (tid >> 4)) * cN + n0 + (tid & 15)];
    __syncthreads();
    float s = 0.f;
    #pragma unroll
    for (int t = 0; t < cT; t++) s += L[tx][t] * R[ty][t];
    s += bss[tx][ty];
    float sig = 1.f / (1.f + expf(-s));
    Pt[((size_t)b * cN + n0 + ty) * cN + m0 + tx] = f2bf(sig);
}

// ---------------------------------------------------------------------------
// Batched bf16 MFMA GEMM, 128x128 tile, BK=32, 4 waves, 16x16x32 MFMA.
// A[m][k] bf16 row-major (k-contig), Bt[n][k] bf16 (k-contig, i.e. B^T).
// CM==0: C f32 (flags doAcc/doRelu). CM==1: C bf16.
template<int CM>
__global__ __launch_bounds__(256) void k_mfma_gemm(
    const unsigned short* __restrict__ A, int lda, long long aStride,
    const unsigned short* __restrict__ Bt, int ldb, long long bStride,
    void* __restrict__ Cv, int ldc, long long cStride,
    int K, int doAcc, int doRelu)
{
    __shared__ unsigned short As[128][40];  // +8 pad: 2-way-max bank pattern
    __shared__ unsigned short Bs[128][40];
    int tid = threadIdx.x;
    int bn = blockIdx.x * 128;
    int bm = blockIdx.y * 128;
    int z  = blockIdx.z;
    const unsigned short* Ap = A  + (size_t)z * aStride;
    const unsigned short* Bp = Bt + (size_t)z * bStride;

    int lane = tid & 63, w = tid >> 6;
    int wm = (w >> 1) * 64, wn = (w & 1) * 64;
    int fr = lane & 15, kg = (lane >> 4) * 8;

    f32x4 acc[4][4] = {};

    int c0 = tid, c1 = tid + 256;
    int r0 = c0 >> 2, g0 = (c0 & 3) * 8;
    int r1 = c1 >> 2, g1 = (c1 & 3) * 8;

    for (int k0 = 0; k0 < K; k0 += 32) {
        u16x8 a0 = *(const u16x8*)(Ap + (size_t)(bm + r0) * lda + k0 + g0);
        u16x8 a1 = *(const u16x8*)(Ap + (size_t)(bm + r1) * lda + k0 + g1);
        u16x8 b0 = *(const u16x8*)(Bp + (size_t)(bn + r0) * ldb + k0 + g0);
        u16x8 b1 = *(const u16x8*)(Bp + (size_t)(bn + r1) * ldb + k0 + g1);
        __syncthreads();   // previous iter's LDS reads done
        *(u16x8*)&As[r0][g0] = a0;
        *(u16x8*)&As[r1][g1] = a1;
        *(u16x8*)&Bs[r0][g0] = b0;
        *(u16x8*)&Bs[r1][g1] = b1;
        __syncthreads();
        s16x8 af[4], bf[4];
        #pragma unroll
        for (int i = 0; i < 4; i++)
            af[i] = *(const s16x8*)&As[wm + i * 16 + fr][kg];
        #pragma unroll
        for (int j = 0; j < 4; j++)
            bf[j] = *(const s16x8*)&Bs[wn + j * 16 + fr][kg];
        #pragma unroll
        for (int i = 0; i < 4; i++)
            #pragma unroll
            for (int j = 0; j < 4; j++)
                acc[i][j] = __builtin_amdgcn_mfma_f32_16x16x32_bf16(
                    af[i], bf[j], acc[i][j], 0, 0, 0);
    }
    int rb = (lane >> 4) * 4;
    if (CM == 0) {
        float* Cp = (float*)Cv + (size_t)z * cStride;
        #pragma unroll
        for (int i = 0; i < 4; i++) {
            int row = bm + wm + i * 16 + rb;
            #pragma unroll
            for (int j = 0; j < 4; j++) {
                int col = bn + wn + j * 16 + fr;
                #pragma unroll
                for (int r = 0; r < 4; r++) {
                    size_t idx = (size_t)(row + r) * ldc + col;
                    float v = acc[i][j][r];
                    if (doAcc) v += Cp[idx];
                    if (doRelu) v = fmaxf(v, 0.f);
                    Cp[idx] = v;
                }
            }
        }
    } else {
        unsigned short* Cp = (unsigned short*)Cv + (size_t)z * cStride;
        #pragma unroll
        for (int i = 0; i < 4; i++) {
            int row = bm + wm + i * 16 + rb;
            #pragma unroll
            for (int j = 0; j < 4; j++) {
                int col = bn + wn + j * 16 + fr;
                #pragma unroll
                for (int r = 0; r < 4; r++)
                    Cp[(size_t)(row + r) * ldc + col] = f2bf(acc[i][j][r]);
            }
        }
    }
}

// ---------------------------------------------------------------------------
// Row softmax over 512 columns, in place (f32).
__global__ __launch_bounds__(256) void k_softmax512(float* __restrict__ S)
{
    int row = blockIdx.x;
    int tid = threadIdx.x;
    float* p = S + (size_t)row * cN;
    float v0 = p[tid], v1 = p[tid + 256];
    __shared__ float red[256];
    red[tid] = fmaxf(v0, v1);
    __syncthreads();
    for (int off = 128; off > 0; off >>= 1) {
        if (tid < off) red[tid] = fmaxf(red[tid], red[tid + off]);
        __syncthreads();
    }
    float mx = red[0];
    __syncthreads();
    float e0 = expf(v0 - mx), e1 = expf(v1 - mx);
    red[tid] = e0 + e1;
    __syncthreads();
    for (int off = 128; off > 0; off >>= 1) {
        if (tid < off) red[tid] += red[tid + off];
        __syncthreads();
    }
    float inv = 1.f / red[0];
    p[tid] = e0 * inv;
    p[tid + 256] = e1 * inv;
}

// ---------------------------------------------------------------------------
// St[b,n,q] = bf16(S0[b,q,n])  (64x64 tiled transpose, f32 -> bf16)
__global__ __launch_bounds__(256) void k_transpose_S(
    const float* __restrict__ S0, unsigned short* __restrict__ St)
{
    int b = blockIdx.z;
    int q0 = blockIdx.y * 64, n0 = blockIdx.x * 64;
    __shared__ float t[64][68];
    int tid = threadIdx.x;
    int r = tid >> 2, grp = (tid & 3) * 16;
    const float* ip = S0 + ((size_t)b * cN + q0 + r) * cN + n0 + grp;
    #pragma unroll
    for (int i = 0; i < 16; i += 4)
        *(float4*)&t[r][grp + i] = *(const float4*)(ip + i);
    __syncthreads();
    int nr = tid & 63, qg = (tid >> 6) * 16;
    unsigned short* op = St + ((size_t)b * cN + n0 + nr) * cN + q0 + qg;
    u16x8 v0, v1;
    #pragma unroll
    for (int i = 0; i < 8; i++) {
        v0[i] = f2bf(t[qg + i][nr]);
        v1[i] = f2bf(t[qg + 8 + i][nr]);
    }
    *(u16x8*)op = v0;
    *(u16x8*)(op + 8) = v1;
}

// ---------------------------------------------------------------------------
// XTn[b,n',j] = bf16( sum_c x[b,n,c,t]*Theta[k,c,f] ),  j=f*24+t, n=hf*256+n'
__global__ __launch_bounds__(256) void k_xtheta_bf(
    const float* __restrict__ x, const float* __restrict__ Theta,
    int k, int hf, unsigned short* __restrict__ XTn)
{
    int idx = blockIdx.x;            // b*256 + n'
    int b = idx >> 8, np = idx & 255;
    int n = hf * 256 + np;
    int tid = threadIdx.x;
    __shared__ float xs[64][25];
    __shared__ float th[64 * 64];
    __shared__ float outs[64 * 25];
    const float* xp = x + ((size_t)b * cN + n) * cCT;
    for (int i = tid; i < cCT; i += 256) xs[i / cT][i % cT] = xp[i];
    const float* tp = Theta + (size_t)k * cC * cF;
    for (int i = tid; i < cC * cF; i += 256) th[i] = tp[i];
    __syncthreads();
    int f = tid & 63, g = tid >> 6;
    #pragma unroll
    for (int j = 0; j < 6; j++) {
        int t = g * 6 + j;
        float s = 0.f;
        #pragma unroll
        for (int c = 0; c < 64; c++) s += xs[c][t] * th[c * 64 + f];
        outs[f * 25 + t] = s;
    }
    __syncthreads();
    unsigned short* op = XTn + ((size_t)b * 256 + np) * cFT;
    for (int i = tid; i < cFT; i += 256)
        op[i] = f2bf(outs[(i / cT) * 25 + i % cT]);
}

// ---------------------------------------------------------------------------
// XTt[b,j,hf*256+n'] = XTn[b,n',j]   (64x64 bf16 tiled transpose)
__global__ __launch_bounds__(256) void k_transpose_xt(
    const unsigned short* __restrict__ XTn, int hf,
    unsigned short* __restrict__ XTt)
{
    int b = blockIdx.z;
    int n0 = blockIdx.x * 64;   // n' tile (grid.x = 4)
    int j0 = blockIdx.y * 64;   // j tile  (grid.y = 24)
    __shared__ unsigned short t[64][72];
    int tid = threadIdx.x;
    int r = tid >> 2, grp = (tid & 3) * 16;
    const unsigned short* ip = XTn + ((size_t)b * 256 + n0 + r) * cFT + j0 + grp;
    *(u16x8*)&t[r][grp]     = *(const u16x8*)(ip);
    *(u16x8*)&t[r][grp + 8] = *(const u16x8*)(ip + 8);
    __syncthreads();
    int jr = tid & 63, ng = (tid >> 6) * 16;
    unsigned short* op = XTt + ((size_t)b * cFT + j0 + jr) * cN + hf * 256 + n0 + ng;
    u16x8 v0, v1;
    #pragma unroll
    for (int i = 0; i < 8; i++) {
        v0[i] = t[ng + i][jr];
        v1[i] = t[ng + 8 + i][jr];
    }
    *(u16x8*)op = v0;
    *(u16x8*)(op + 8) = v1;
}

// ---------------------------------------------------------------------------
// f32 -> bf16 elementwise
__global__ void k_convert(const float* __restrict__ a,
                          unsigned short* __restrict__ o, int n)
{
    int i = blockIdx.x * 256 + threadIdx.x;
    if (i < n) o[i] = f2bf(a[i]);
}

// ---------------------------------------------------------------------------
// partial hU1: part[b,nc,f,t] = sum_{n in chunk} U1[n]*h[b,n,f,t]
__global__ __launch_bounds__(256) void k_hU1_part(
    const float* __restrict__ h, const float* __restrict__ U1,
    float* __restrict__ part)
{
    int b = blockIdx.x, nc = blockIdx.y;
    int tid = threadIdx.x;
    int f = tid & 63, q = tid >> 6;
    float acc[24];
    #pragma unroll
    for (int t = 0; t < 24; t++) acc[t] = 0.f;
    for (int n = nc * 32 + q; n < nc * 32 + 32; n += 4) {
        float u = U1[n];
        const float4* hp = (const float4*)(h + (((size_t)b * cN + n) * cF + f) * cT);
        #pragma unroll
        for (int v4 = 0; v4 < 6; v4++) {
            float4 hv = hp[v4];
            acc[v4 * 4 + 0] += u * hv.x;
            acc[v4 * 4 + 1] += u * hv.y;
            acc[v4 * 4 + 2] += u * hv.z;
            acc[v4 * 4 + 3] += u * hv.w;
        }
    }
    __shared__ float ps[4][64][25];
    #pragma unroll
    for (int t = 0; t < 24; t++) ps[q][f][t] = acc[t];
    __syncthreads();
    for (int i = tid; i < cFT; i += 256) {
        int f2 = i / cT, t2 = i % cT;
        float s = ps[0][f2][t2] + ps[1][f2][t2] + ps[2][f2][t2] + ps[3][f2][t2];
        part[(((size_t)b * 16 + nc) * cF + f2) * cT + t2] = s;
    }
}

// ---------------------------------------------------------------------------
__global__ __launch_bounds__(256) void k_lhs_t(
    const float* __restrict__ part, const float* __restrict__ U2,
    float* __restrict__ lhs_t)
{
    int b = blockIdx.x, ch = blockIdx.y;
    int tid = threadIdx.x;
    __shared__ float hu[1536];
    for (int i = tid; i < 1536; i += 256) {
        float s = 0.f;
        for (int nc = 0; nc < 16; nc++)
            s += part[((size_t)b * 16 + nc) * 1536 + i];
        hu[i] = s;
    }
    __syncthreads();
    int nn0 = ch * 128;
    for (int i = tid; i < cT * 128; i += 256) {
        int t = i / 128, nn = nn0 + (i % 128);
        float s = 0.f;
        #pragma unroll
        for (int f = 0; f < 64; f++) s += hu[f * cT + t] * U2[(size_t)f * cN + nn];
        lhs_t[((size_t)b * cT + t) * cN + nn] = s;
    }
}

// ---------------------------------------------------------------------------
__global__ __launch_bounds__(64) void k_rhs_t(
    const float* __restrict__ h, const float* __restrict__ U3,
    float* __restrict__ rhs_t)
{
    int bn = blockIdx.x;
    int f = threadIdx.x;
    __shared__ float sl[64][25];
    const float4* hp = (const float4*)(h + (size_t)bn * cFT + f * cT);
    float u = U3[f];
    #pragma unroll
    for (int v4 = 0; v4 < 6; v4++) {
        float4 hv = hp[v4];
        sl[f][v4 * 4 + 0] = u * hv.x;
        sl[f][v4 * 4 + 1] = u * hv.y;
        sl[f][v4 * 4 + 2] = u * hv.z;
        sl[f][v4 * 4 + 3] = u * hv.w;
    }
    __syncthreads();
    if (f < cT) {
        float s = 0.f;
        #pragma unroll
        for (int c = 0; c < 64; c++) s += sl[c][f];
        rhs_t[(size_t)bn * cT + f] = s;
    }
}

// ---------------------------------------------------------------------------
__global__ __launch_bounds__(576) void k_E(
    const float* __restrict__ lhs_t, const float* __restrict__ rhs_t,
    const float* __restrict__ be, const float* __restrict__ Ve,
    float* __restrict__ E)
{
    int b = blockIdx.x;
    int tid = threadIdx.x;
    int i = tid / 24, j = tid % 24;
    __shared__ float ps[24][25];
    __shared__ float er[24][25];
    __shared__ float mrow[24], srow[24];
    const float* lp = lhs_t + ((size_t)b * cT + i) * cN;
    const float* rp = rhs_t + (size_t)b * cN * cT;
    float s = 0.f;
    for (int n = 0; n < cN; n++) s += lp[n] * rp[n * cT + j];
    s += be[i * cT + j];
    ps[i][j] = 1.f / (1.f + expf(-s));
    __syncthreads();
    float e = 0.f;
    #pragma unroll
    for (int ss = 0; ss < cT; ss++) e += Ve[i * cT + ss] * ps[ss][j];
    er[i][j] = e;
    __syncthreads();
    if (j == 0) {
        float m = -1e30f;
        for (int r = 0; r < cT; r++) m = fmaxf(m, er[i][r]);
        float sm = 0.f;
        for (int r = 0; r < cT; r++) sm += expf(er[i][r] - m);
        mrow[i] = m;
        srow[i] = sm;
    }
    __syncthreads();
    E[(size_t)b * cT * cT + i * cT + j] = expf(er[i][j] - mrow[i]) / srow[i];
}

// ---------------------------------------------------------------------------
__global__ __launch_bounds__(256) void k_tmix(float* __restrict__ h,
                                              const float* __restrict__ E)
{
    int bn = blockIdx.x;
    int b = bn >> 9;
    int tid = threadIdx.x;
    __shared__ float hs[64][25];
    __shared__ float Es[24][24];
    __shared__ float outs[64 * 25];
    float* hp = h + (size_t)bn * cFT;
    for (int i = tid; i < cFT; i += 256) hs[i / cT][i % cT] = hp[i];
    for (int i = tid; i < 576; i += 256)
        Es[i / 24][i % 24] = E[(size_t)b * 576 + i];
    __syncthreads();
    int f = tid & 63, g = tid >> 6;
    #pragma unroll
    for (int j = 0; j < 6; j++) {
        int so = g * 6 + j;
        float s = 0.f;
        #pragma unroll
        for (int t = 0; t < cT; t++) s += hs[f][t] * Es[t][so];
        outs[f * 25 + so] = s;
    }
    __syncthreads();
    for (int i = tid; i < cFT; i += 256) hp[i] = outs[(i / cT) * 25 + i % cT];
}

// ---------------------------------------------------------------------------
__global__ __launch_bounds__(256) void k_convln(
    float* __restrict__ h, const float* __restrict__ x,
    const float* __restrict__ cw, const float* __restrict__ cb,
    const float* __restrict__ lnw, const float* __restrict__ lnb)
{
    int bn = blockIdx.x;
    int tid = threadIdx.x;
    int f = tid & 63, g = tid >> 6;
    __shared__ float hs[64][26];
    __shared__ float wT[64 * 64 * 3];
    __shared__ float xs2[64 * 25];
    __shared__ float outs[64 * 25];
    float* hp = h + (size_t)bn * cFT;
    for (int i = tid; i < cFT; i += 256) hs[i / cT][1 + i % cT] = hp[i];
    if (tid < 64) { hs[tid][0] = 0.f; hs[tid][25] = 0.f; }
    const float* xp = x + (size_t)bn * cCT;
    for (int i = tid; i < cCT; i += 256) xs2[(i / cT) * 25 + i % cT] = xp[i];
    for (int i = tid; i < 64 * 64 * 3; i += 256) {
        int ff = i / 192, rest = i % 192;
        int fi = rest / 3, d = rest % 3;
        wT[(fi * 64 + ff) * 3 + d] = cw[i];
    }
    __syncthreads();
    float acc[6];
    float bias = cb[f];
    #pragma unroll
    for (int j = 0; j < 6; j++) acc[j] = bias;
    for (int fi = 0; fi < 64; fi++) {
        float r[8];
        #pragma unroll
        for (int c = 0; c < 8; c++) r[c] = hs[fi][g * 6 + c];
        float w0 = wT[(fi * 64 + f) * 3 + 0];
        float w1 = wT[(fi * 64 + f) * 3 + 1];
        float w2 = wT[(fi * 64 + f) * 3 + 2];
        #pragma unroll
        for (int j = 0; j < 6; j++) acc[j] += w0 * r[j] + w1 * r[j + 1] + w2 * r[j + 2];
    }
    float w_ln = lnw[f], b_ln = lnb[f];
    #pragma unroll
    for (int j = 0; j < 6; j++) {
        int t = g * 6 + j;
        float v = acc[j] + xs2[f * 25 + t];
        float s1 = v, s2 = v * v;
        #pragma unroll
        for (int off = 1; off < 64; off <<= 1) {
            s1 += __shfl_xor(s1, off, 64);
            s2 += __shfl_xor(s2, off, 64);
        }
        float mean = s1 * (1.f / 64.f);
        float var = s2 * (1.f / 64.f) - mean * mean;
        float rstd = rsqrtf(var + 1e-5f);
        outs[f * 25 + t] = (v - mean) * rstd * w_ln + b_ln;
    }
    __syncthreads();
    for (int i = tid; i < cFT; i += 256) hp[i] = outs[(i / cT) * 25 + i % cT];
}

// ---------------------------------------------------------------------------
extern "C" void kernel_launch(void* const* d_in, const int* in_sizes, int n_in,
                              void* d_out, int out_size, void* d_ws, size_t ws_size,
                              hipStream_t stream)
{
    const float* x     = (const float*)d_in[0];
    const float* cheb  = (const float*)d_in[1];
    const float* W1    = (const float*)d_in[2];
    const float* W2    = (const float*)d_in[3];
    const float* W3    = (const float*)d_in[4];
    const float* bs    = (const float*)d_in[5];
    const float* Vs    = (const float*)d_in[6];
    const float* U1    = (const float*)d_in[7];
    const float* U2    = (const float*)d_in[8];
    const float* U3    = (const float*)d_in[9];
    const float* be    = (const float*)d_in[10];
    const float* Ve    = (const float*)d_in[11];
    const float* Theta = (const float*)d_in[12];
    const float* cw    = (const float*)d_in[13];
    const float* cbp   = (const float*)d_in[14];
    const float* lnw   = (const float*)d_in[15];
    const float* lnb   = (const float*)d_in[16];
    float* out = (float*)d_out;
    float* ws  = (float*)d_ws;

    // workspace layout (f32-slot offsets); total ~126 MB
    unsigned short* Vs_bf   = (unsigned short*)(ws);              // 262144 u16
    unsigned short* cheb_bf = (unsigned short*)(ws + 131072);     // 786432 u16
    float*  lhs  = ws + 524288;     // 393216 (later lhs_t)
    float*  rhs  = ws + 917504;     // 393216 (later rhs_t)
    float*  part = ws + 1310720;    // 786432
    float*  Ebuf = ws + 2097152;    // 18432
    float*  S0   = ws + 2115584;    // 8388608 f32  (bufA; reused as XTn 12.6M u16)
    unsigned short* XTn = (unsigned short*)S0;
    unsigned short* Pt  = (unsigned short*)(ws + 10504192);       // bufB 8.4M u16
    unsigned short* St  = Pt;                                     // reuse after GEMM1
    unsigned short* Wk  = (unsigned short*)(ws + 14698496);       // 8.4M u16
    unsigned short* XTt = (unsigned short*)(ws + 18892800);       // 25.2M u16

    const long long NN2 = (long long)cN * cN;      // 262144
    const long long NJT = (long long)cFT * cN;     // 786432 (XTt per-b)
    const long long NFT = (long long)cN * cFT;     // 786432 (h per-b)

    // bf16 parameter copies
    k_convert<<<1024, 256, 0, stream>>>(Vs, Vs_bf, 262144);
    k_convert<<<3072, 256, 0, stream>>>(cheb, cheb_bf, 786432);

    // spatial attention
    k_spatial_lr<<<cB * cN, 64, 0, stream>>>(x, W1, W2, W3, lhs, rhs);
    k_product_t<<<dim3(32, 32, cB), dim3(16, 16), 0, stream>>>(lhs, rhs, bs, Pt);
    // S0 = Vs_bf @ P  (B^T = Pt)
    k_mfma_gemm<0><<<dim3(4, 4, cB), 256, 0, stream>>>(
        Vs_bf, 512, 0LL, Pt, 512, NN2, S0, 512, NN2, 512, 0, 0);
    k_softmax512<<<cB * cN, 256, 0, stream>>>(S0);
    k_transpose_S<<<dim3(8, 8, cB), 256, 0, stream>>>(S0, St);

    // Cheb conv: per k: XT_k (2 halves) -> W_k = cheb_k @ S -> h (+)= W_k @ XT_k
    for (int k = 0; k < cK; k++) {
        for (int hf = 0; hf < 2; hf++) {
            k_xtheta_bf<<<cB * 256, 256, 0, stream>>>(x, Theta, k, hf, XTn);
            k_transpose_xt<<<dim3(4, 24, cB), 256, 0, stream>>>(XTn, hf, XTt);
        }
        k_mfma_gemm<1><<<dim3(4, 4, cB), 256, 0, stream>>>(
            cheb_bf + (size_t)k * NN2, 512, 0LL, St, 512, NN2,
            Wk, 512, NN2, 512, 0, 0);
        k_mfma_gemm<0><<<dim3(12, 4, cB), 256, 0, stream>>>(
            Wk, 512, NN2, XTt, 512, NJT, out, 1536, NFT, 512,
            (k > 0) ? 1 : 0, (k == 2) ? 1 : 0);
    }

    // temporal attention + mixing + conv + LN
    k_hU1_part<<<dim3(cB, 16), 256, 0, stream>>>(out, U1, part);
    k_rhs_t<<<cB * cN, 64, 0, stream>>>(out, U3, rhs);
    k_lhs_t<<<dim3(cB, 4), 256, 0, stream>>>(part, U2, lhs);
    k_E<<<cB, 576, 0, stream>>>(lhs, rhs, be, Ve, Ebuf);
    k_tmix<<<cB * cN, 256, 0, stream>>>(out, Ebuf);
    k_convln<<<cB * cN, 256, 0, stream>>>(out, x, cw, cbp, lnw, lnb);
}

// Round 4
// 1487.467 us; speedup vs baseline: 2.1719x; 1.2662x over previous
//
#include <hip/hip_runtime.h>

// Problem constants
constexpr int cB = 32, cN = 512, cC = 64, cT = 24, cK = 3, cF = 64;
constexpr int cCT = cC * cT;   // 1536
constexpr int cFT = cF * cT;   // 1536

typedef __attribute__((ext_vector_type(8))) short s16x8;            // MFMA bf16 frag
typedef __attribute__((ext_vector_type(8))) unsigned short u16x8;   // 16B load/store
typedef __attribute__((ext_vector_type(4))) float f32x4;            // MFMA acc

__device__ inline unsigned short f2bf(float f) {
    union { float f; unsigned int u; } v; v.f = f;
    unsigned int r = v.u + 0x7FFFu + ((v.u >> 16) & 1u);
    return (unsigned short)(r >> 16);
}

// ---------------------------------------------------------------------------
__global__ __launch_bounds__(64) void k_spatial_lr(
    const float* __restrict__ x, const float* __restrict__ W1,
    const float* __restrict__ W2, const float* __restrict__ W3,
    float* __restrict__ lhs, float* __restrict__ rhs)
{
    int bn = blockIdx.x;
    int tid = threadIdx.x;
    __shared__ float xs[64][25];
    __shared__ float a_sh[64];
    const float* xp = x + (size_t)bn * cCT;
    for (int i = tid; i < cCT; i += 64) xs[i / cT][i % cT] = xp[i];
    __syncthreads();
    float s = 0.f;
    #pragma unroll
    for (int t = 0; t < cT; t++) s += xs[tid][t] * W1[t];
    a_sh[tid] = s;
    __syncthreads();
    if (tid < cT) {
        float l = 0.f, r = 0.f;
        for (int c = 0; c < cC; c++) {
            l += a_sh[c] * W2[c * cT + tid];
            r += xs[c][tid] * W3[c];
        }
        lhs[(size_t)bn * cT + tid] = l;
        rhs[(size_t)bn * cT + tid] = r;
    }
}

// ---------------------------------------------------------------------------
// Pt[b,n,m] = bf16(sigmoid(sum_t lhs[b,m,t]*rhs[b,n,t] + bs[m,n]))  (transposed)
__global__ __launch_bounds__(256) void k_product_t(
    const float* __restrict__ lhs, const float* __restrict__ rhs,
    const float* __restrict__ bs, unsigned short* __restrict__ Pt)
{
    int b = blockIdx.z;
    int m0 = blockIdx.y * 16, n0 = blockIdx.x * 16;
    int tx = threadIdx.x, ty = threadIdx.y;
    int tid = ty * 16 + tx;
    __shared__ float L[16][25], R[16][25], bss[16][17];
    for (int i = tid; i < 16 * cT; i += 256) {
        int r = i / cT, c = i % cT;
        L[r][c] = lhs[((size_t)b * cN + m0 + r) * cT + c];
        R[r][c] = rhs[((size_t)b * cN + n0 + r) * cT + c];
    }
    bss[tid >> 4][tid & 15] = bs[(size_t)(m0 + (tid >> 4)) * cN + n0 + (tid & 15)];
    __syncthreads();
    float s = 0.f;
    #pragma unroll
    for (int t = 0; t < cT; t++) s += L[tx][t] * R[ty][t];
    s += bss[tx][ty];
    float sig = 1.f / (1.f + expf(-s));
    Pt[((size_t)b * cN + n0 + ty) * cN + m0 + tx] = f2bf(sig);
}

// ---------------------------------------------------------------------------
// Batched bf16 MFMA GEMM, 128x128 tile, BK=32, 4 waves, 16x16x32 MFMA.
template<int CM>
__global__ __launch_bounds__(256) void k_mfma_gemm(
    const unsigned short* __restrict__ A, int lda, long long aB,
    const unsigned short* __restrict__ Bt, int ldb, long long bB,
    void* __restrict__ Cv, int ldc, long long cBs,
    int K, int doAcc, int doRelu)
{
    __shared__ unsigned short As[128][40];
    __shared__ unsigned short Bs[128][40];
    int tid = threadIdx.x;
    int bn = blockIdx.x * 128;
    int bm = blockIdx.y * 128;
    int z  = blockIdx.z;
    const unsigned short* Ap = A  + (size_t)z * aB;
    const unsigned short* Bp = Bt + (size_t)z * bB;

    int lane = tid & 63, w = tid >> 6;
    int wm = (w >> 1) * 64, wn = (w & 1) * 64;
    int fr = lane & 15, kg = (lane >> 4) * 8;

    f32x4 acc[4][4] = {};

    int c0 = tid, c1 = tid + 256;
    int r0 = c0 >> 2, g0 = (c0 & 3) * 8;
    int r1 = c1 >> 2, g1 = (c1 & 3) * 8;

    for (int k0 = 0; k0 < K; k0 += 32) {
        u16x8 a0 = *(const u16x8*)(Ap + (size_t)(bm + r0) * lda + k0 + g0);
        u16x8 a1 = *(const u16x8*)(Ap + (size_t)(bm + r1) * lda + k0 + g1);
        u16x8 b0 = *(const u16x8*)(Bp + (size_t)(bn + r0) * ldb + k0 + g0);
        u16x8 b1 = *(const u16x8*)(Bp + (size_t)(bn + r1) * ldb + k0 + g1);
        __syncthreads();
        *(u16x8*)&As[r0][g0] = a0;
        *(u16x8*)&As[r1][g1] = a1;
        *(u16x8*)&Bs[r0][g0] = b0;
        *(u16x8*)&Bs[r1][g1] = b1;
        __syncthreads();
        s16x8 af[4], bf[4];
        #pragma unroll
        for (int i = 0; i < 4; i++)
            af[i] = *(const s16x8*)&As[wm + i * 16 + fr][kg];
        #pragma unroll
        for (int j = 0; j < 4; j++)
            bf[j] = *(const s16x8*)&Bs[wn + j * 16 + fr][kg];
        #pragma unroll
        for (int i = 0; i < 4; i++)
            #pragma unroll
            for (int j = 0; j < 4; j++)
                acc[i][j] = __builtin_amdgcn_mfma_f32_16x16x32_bf16(
                    af[i], bf[j], acc[i][j], 0, 0, 0);
    }
    int rb = (lane >> 4) * 4;
    if (CM == 0) {
        float* Cp = (float*)Cv + (size_t)z * cBs;
        #pragma unroll
        for (int i = 0; i < 4; i++) {
            int row = bm + wm + i * 16 + rb;
            #pragma unroll
            for (int j = 0; j < 4; j++) {
                int col = bn + wn + j * 16 + fr;
                #pragma unroll
                for (int r = 0; r < 4; r++) {
                    size_t idx = (size_t)(row + r) * ldc + col;
                    float v = acc[i][j][r];
                    if (doAcc) v += Cp[idx];
                    if (doRelu) v = fmaxf(v, 0.f);
                    Cp[idx] = v;
                }
            }
        }
    } else {
        unsigned short* Cp = (unsigned short*)Cv + (size_t)z * cBs;
        #pragma unroll
        for (int i = 0; i < 4; i++) {
            int row = bm + wm + i * 16 + rb;
            #pragma unroll
            for (int j = 0; j < 4; j++) {
                int col = bn + wn + j * 16 + fr;
                #pragma unroll
                for (int r = 0; r < 4; r++)
                    Cp[(size_t)(row + r) * ldc + col] = f2bf(acc[i][j][r]);
            }
        }
    }
}

// ---------------------------------------------------------------------------
__global__ __launch_bounds__(256) void k_softmax512(float* __restrict__ S)
{
    int row = blockIdx.x;
    int tid = threadIdx.x;
    float* p = S + (size_t)row * cN;
    float v0 = p[tid], v1 = p[tid + 256];
    __shared__ float red[256];
    red[tid] = fmaxf(v0, v1);
    __syncthreads();
    for (int off = 128; off > 0; off >>= 1) {
        if (tid < off) red[tid] = fmaxf(red[tid], red[tid + off]);
        __syncthreads();
    }
    float mx = red[0];
    __syncthreads();
    float e0 = expf(v0 - mx), e1 = expf(v1 - mx);
    red[tid] = e0 + e1;
    __syncthreads();
    for (int off = 128; off > 0; off >>= 1) {
        if (tid < off) red[tid] += red[tid + off];
        __syncthreads();
    }
    float inv = 1.f / red[0];
    p[tid] = e0 * inv;
    p[tid + 256] = e1 * inv;
}

// ---------------------------------------------------------------------------
__global__ __launch_bounds__(256) void k_transpose_S(
    const float* __restrict__ S0, unsigned short* __restrict__ St)
{
    int b = blockIdx.z;
    int q0 = blockIdx.y * 64, n0 = blockIdx.x * 64;
    __shared__ float t[64][68];
    int tid = threadIdx.x;
    int r = tid >> 2, grp = (tid & 3) * 16;
    const float* ip = S0 + ((size_t)b * cN + q0 + r) * cN + n0 + grp;
    #pragma unroll
    for (int i = 0; i < 16; i += 4)
        *(float4*)&t[r][grp + i] = *(const float4*)(ip + i);
    __syncthreads();
    int nr = tid & 63, qg = (tid >> 6) * 16;
    unsigned short* op = St + ((size_t)b * cN + n0 + nr) * cN + q0 + qg;
    u16x8 v0, v1;
    #pragma unroll
    for (int i = 0; i < 8; i++) {
        v0[i] = f2bf(t[qg + i][nr]);
        v1[i] = f2bf(t[qg + 8 + i][nr]);
    }
    *(u16x8*)op = v0;
    *(u16x8*)(op + 8) = v1;
}

// ---------------------------------------------------------------------------
__global__ __launch_bounds__(256) void k_xtheta_bf(
    const float* __restrict__ x, const float* __restrict__ Theta,
    int k, int hf, unsigned short* __restrict__ XTn)
{
    int idx = blockIdx.x;
    int b = idx >> 8, np = idx & 255;
    int n = hf * 256 + np;
    int tid = threadIdx.x;
    __shared__ float xs[64][25];
    __shared__ float th[64 * 64];
    __shared__ float outs[64 * 25];
    const float* xp = x + ((size_t)b * cN + n) * cCT;
    for (int i = tid; i < cCT; i += 256) xs[i / cT][i % cT] = xp[i];
    const float* tp = Theta + (size_t)k * cC * cF;
    for (int i = tid; i < cC * cF; i += 256) th[i] = tp[i];
    __syncthreads();
    int f = tid & 63, g = tid >> 6;
    #pragma unroll
    for (int j = 0; j < 6; j++) {
        int t = g * 6 + j;
        float s = 0.f;
        #pragma unroll
        for (int c = 0; c < 64; c++) s += xs[c][t] * th[c * 64 + f];
        outs[f * 25 + t] = s;
    }
    __syncthreads();
    unsigned short* op = XTn + ((size_t)b * 256 + np) * cFT;
    for (int i = tid; i < cFT; i += 256)
        op[i] = f2bf(outs[(i / cT) * 25 + i % cT]);
}

// ---------------------------------------------------------------------------
__global__ __launch_bounds__(256) void k_transpose_xt(
    const unsigned short* __restrict__ XTn, int hf,
    unsigned short* __restrict__ XTt)
{
    int b = blockIdx.z;
    int n0 = blockIdx.x * 64;
    int j0 = blockIdx.y * 64;
    __shared__ unsigned short t[64][72];
    int tid = threadIdx.x;
    int r = tid >> 2, grp = (tid & 3) * 16;
    const unsigned short* ip = XTn + ((size_t)b * 256 + n0 + r) * cFT + j0 + grp;
    *(u16x8*)&t[r][grp]     = *(const u16x8*)(ip);
    *(u16x8*)&t[r][grp + 8] = *(const u16x8*)(ip + 8);
    __syncthreads();
    int jr = tid & 63, ng = (tid >> 6) * 16;
    unsigned short* op = XTt + ((size_t)b * cFT + j0 + jr) * cN + hf * 256 + n0 + ng;
    u16x8 v0, v1;
    #pragma unroll
    for (int i = 0; i < 8; i++) {
        v0[i] = t[ng + i][jr];
        v1[i] = t[ng + 8 + i][jr];
    }
    *(u16x8*)op = v0;
    *(u16x8*)(op + 8) = v1;
}

// ---------------------------------------------------------------------------
__global__ void k_convert(const float* __restrict__ a,
                          unsigned short* __restrict__ o, int n)
{
    int i = blockIdx.x * 256 + threadIdx.x;
    if (i < n) o[i] = f2bf(a[i]);
}

// ---------------------------------------------------------------------------
// W2g[f][d*64+fi] = bf16(conv_w[f][fi][0][d])
__global__ void k_wprep(const float* __restrict__ cw,
                        unsigned short* __restrict__ W2g)
{
    int i = blockIdx.x * 256 + threadIdx.x;
    if (i < 64 * 192) {
        int f = i / 192, k = i % 192;
        int d = k >> 6, fi = k & 63;
        W2g[i] = f2bf(cw[f * 192 + fi * 3 + d]);
    }
}

// ---------------------------------------------------------------------------
__global__ __launch_bounds__(256) void k_hU1_part(
    const float* __restrict__ h, const float* __restrict__ U1,
    float* __restrict__ part)
{
    int b = blockIdx.x, nc = blockIdx.y;
    int tid = threadIdx.x;
    int f = tid & 63, q = tid >> 6;
    float acc[24];
    #pragma unroll
    for (int t = 0; t < 24; t++) acc[t] = 0.f;
    for (int n = nc * 32 + q; n < nc * 32 + 32; n += 4) {
        float u = U1[n];
        const float4* hp = (const float4*)(h + (((size_t)b * cN + n) * cF + f) * cT);
        #pragma unroll
        for (int v4 = 0; v4 < 6; v4++) {
            float4 hv = hp[v4];
            acc[v4 * 4 + 0] += u * hv.x;
            acc[v4 * 4 + 1] += u * hv.y;
            acc[v4 * 4 + 2] += u * hv.z;
            acc[v4 * 4 + 3] += u * hv.w;
        }
    }
    __shared__ float ps[4][64][25];
    #pragma unroll
    for (int t = 0; t < 24; t++) ps[q][f][t] = acc[t];
    __syncthreads();
    for (int i = tid; i < cFT; i += 256) {
        int f2 = i / cT, t2 = i % cT;
        float s = ps[0][f2][t2] + ps[1][f2][t2] + ps[2][f2][t2] + ps[3][f2][t2];
        part[(((size_t)b * 16 + nc) * cF + f2) * cT + t2] = s;
    }
}

// ---------------------------------------------------------------------------
__global__ __launch_bounds__(256) void k_lhs_t(
    const float* __restrict__ part, const float* __restrict__ U2,
    float* __restrict__ lhs_t)
{
    int b = blockIdx.x, ch = blockIdx.y;
    int tid = threadIdx.x;
    __shared__ float hu[1536];
    for (int i = tid; i < 1536; i += 256) {
        float s = 0.f;
        for (int nc = 0; nc < 16; nc++)
            s += part[((size_t)b * 16 + nc) * 1536 + i];
        hu[i] = s;
    }
    __syncthreads();
    int nn0 = ch * 128;
    for (int i = tid; i < cT * 128; i += 256) {
        int t = i / 128, nn = nn0 + (i % 128);
        float s = 0.f;
        #pragma unroll
        for (int f = 0; f < 64; f++) s += hu[f * cT + t] * U2[(size_t)f * cN + nn];
        lhs_t[((size_t)b * cT + t) * cN + nn] = s;
    }
}

// ---------------------------------------------------------------------------
__global__ __launch_bounds__(64) void k_rhs_t(
    const float* __restrict__ h, const float* __restrict__ U3,
    float* __restrict__ rhs_t)
{
    int bn = blockIdx.x;
    int f = threadIdx.x;
    __shared__ float sl[64][25];
    const float4* hp = (const float4*)(h + (size_t)bn * cFT + f * cT);
    float u = U3[f];
    #pragma unroll
    for (int v4 = 0; v4 < 6; v4++) {
        float4 hv = hp[v4];
        sl[f][v4 * 4 + 0] = u * hv.x;
        sl[f][v4 * 4 + 1] = u * hv.y;
        sl[f][v4 * 4 + 2] = u * hv.z;
        sl[f][v4 * 4 + 3] = u * hv.w;
    }
    __syncthreads();
    if (f < cT) {
        float s = 0.f;
        #pragma unroll
        for (int c = 0; c < 64; c++) s += sl[c][f];
        rhs_t[(size_t)bn * cT + f] = s;
    }
}

// ---------------------------------------------------------------------------
__global__ __launch_bounds__(576) void k_E(
    const float* __restrict__ lhs_t, const float* __restrict__ rhs_t,
    const float* __restrict__ be, const float* __restrict__ Ve,
    float* __restrict__ E)
{
    int b = blockIdx.x;
    int tid = threadIdx.x;
    int i = tid / 24, j = tid % 24;
    __shared__ float ps[24][25];
    __shared__ float er[24][25];
    __shared__ float mrow[24], srow[24];
    const float* lp = lhs_t + ((size_t)b * cT + i) * cN;
    const float* rp = rhs_t + (size_t)b * cN * cT;
    float s = 0.f;
    for (int n = 0; n < cN; n++) s += lp[n] * rp[n * cT + j];
    s += be[i * cT + j];
    ps[i][j] = 1.f / (1.f + expf(-s));
    __syncthreads();
    float e = 0.f;
    #pragma unroll
    for (int ss = 0; ss < cT; ss++) e += Ve[i * cT + ss] * ps[ss][j];
    er[i][j] = e;
    __syncthreads();
    if (j == 0) {
        float m = -1e30f;
        for (int r = 0; r < cT; r++) m = fmaxf(m, er[i][r]);
        float sm = 0.f;
        for (int r = 0; r < cT; r++) sm += expf(er[i][r] - m);
        mrow[i] = m;
        srow[i] = sm;
    }
    __syncthreads();
    E[(size_t)b * cT * cT + i * cT + j] = expf(er[i][j] - mrow[i]) / srow[i];
}

// ---------------------------------------------------------------------------
// temporal mixing, emits hT[b,n,t,f] in bf16 (h input unchanged)
__global__ __launch_bounds__(256) void k_tmix_t(
    const float* __restrict__ h, const float* __restrict__ E,
    unsigned short* __restrict__ hT)
{
    int bn = blockIdx.x;
    int b = bn >> 9;
    int tid = threadIdx.x;
    __shared__ float hs[64][25];
    __shared__ float Es[24][24];
    __shared__ float outs[24][65];
    const float* hp = h + (size_t)bn * cFT;
    for (int i = tid; i < cFT; i += 256) hs[i / cT][i % cT] = hp[i];
    for (int i = tid; i < 576; i += 256)
        Es[i / 24][i % 24] = E[(size_t)b * 576 + i];
    __syncthreads();
    int f = tid & 63, g = tid >> 6;
    #pragma unroll
    for (int j = 0; j < 6; j++) {
        int so = g * 6 + j;
        float s = 0.f;
        #pragma unroll
        for (int t = 0; t < cT; t++) s += hs[f][t] * Es[t][so];
        outs[so][f] = s;
    }
    __syncthreads();
    unsigned short* op = hT + (size_t)bn * cFT;
    for (int i = tid; i < cFT; i += 256)
        op[i] = f2bf(outs[i >> 6][i & 63]);
}

// ---------------------------------------------------------------------------
// MFMA conv(1,3) + bias + residual(x) + LayerNorm over F.
// 8 slabs/block, im2col in LDS (K=192), fused in-register LN epilogue.
__global__ __launch_bounds__(256) void k_convmfma(
    const unsigned short* __restrict__ hT,   // [b,n,t,f] bf16
    const float* __restrict__ x,             // [b,n,c,t] f32
    const unsigned short* __restrict__ W2g,  // [f][192] bf16, k=(d*64+fi)
    const float* __restrict__ cb,
    const float* __restrict__ lnw, const float* __restrict__ lnb,
    float* __restrict__ out)                 // [b,n,f,t] f32
{
    __shared__ unsigned short Hs[8][26][72];   // halo rows 0,25 zero; pad 72
    __shared__ unsigned short Ws[64][200];     // pad 200 (400B rows, 16B aligned)
    int tid = threadIdx.x;
    int blk = blockIdx.x;          // 2048
    int b = blk >> 6;
    int n0 = (blk & 63) * 8;
    const unsigned short* hp = hT + ((size_t)b * cN + n0) * cFT;

    // stage hT -> Hs (vectorized, rows shifted +1 for halo)
    #pragma unroll
    for (int it = 0; it < 6; it++) {
        int v = tid + it * 256;        // 1536 vec8 total
        int s = v / 192;
        int r = v % 192;
        int t = r >> 3, f0 = (r & 7) * 8;
        u16x8 val = *(const u16x8*)(hp + (size_t)s * cFT + t * 64 + f0);
        *(u16x8*)&Hs[s][1 + t][f0] = val;
    }
    if (tid < 144) {                   // zero halos: 8 slabs * 2 rows * 9 vec8
        int s = tid / 18, rm = tid % 18;
        int side = rm / 9, c8 = (rm % 9) * 8;
        u16x8 z = {};
        *(u16x8*)&Hs[s][side * 25][c8] = z;
    }
    // stage W2g -> Ws
    #pragma unroll
    for (int it = 0; it < 48; it++) {
        int i = tid + it * 256;        // 12288
        Ws[i / 192][i % 192] = W2g[i];
    }
    __syncthreads();

    int lane = tid & 63, w = tid >> 6;
    int fr = lane & 15, kgrp = lane >> 4;
    f32x4 acc[3][4] = {};

    int sA[3], tA[3];
    #pragma unroll
    for (int mi = 0; mi < 3; mi++) {
        int row = (w * 3 + mi) * 16 + fr;   // A-frag row (0..191)
        sA[mi] = row / 24; tA[mi] = row % 24;
    }
    #pragma unroll
    for (int ks = 0; ks < 6; ks++) {
        int d = ks >> 1;
        int fi0 = (ks & 1) * 32 + kgrp * 8;
        s16x8 bf[4];
        #pragma unroll
        for (int j = 0; j < 4; j++)
            bf[j] = *(const s16x8*)&Ws[j * 16 + fr][ks * 32 + kgrp * 8];
        #pragma unroll
        for (int mi = 0; mi < 3; mi++) {
            s16x8 af = *(const s16x8*)&Hs[sA[mi]][tA[mi] + d][fi0];
            #pragma unroll
            for (int j = 0; j < 4; j++)
                acc[mi][j] = __builtin_amdgcn_mfma_f32_16x16x32_bf16(
                    af, bf[j], acc[mi][j], 0, 0, 0);
        }
    }

    // epilogue: +bias +residual, LN over f (row = (s,t), col f = j*16+fr)
    float lnw_v[4], lnb_v[4], cb_v[4];
    #pragma unroll
    for (int j = 0; j < 4; j++) {
        int f = j * 16 + fr;
        lnw_v[j] = lnw[f]; lnb_v[j] = lnb[f]; cb_v[j] = cb[f];
    }
    #pragma unroll
    for (int mi = 0; mi < 3; mi++) {
        int rowbase = (w * 3 + mi) * 16 + kgrp * 4;   // C-frag rows
        #pragma unroll
        for (int r = 0; r < 4; r++) {
            int row = rowbase + r;
            int s = row / 24, t = row % 24;
            size_t slab = ((size_t)b * cN + n0 + s) * 64;
            float v[4], s1 = 0.f, s2 = 0.f;
            #pragma unroll
            for (int j = 0; j < 4; j++) {
                float xres = x[(slab + j * 16 + fr) * 24 + t];
                v[j] = acc[mi][j][r] + cb_v[j] + xres;
                s1 += v[j];
                s2 += v[j] * v[j];
            }
            #pragma unroll
            for (int off = 1; off < 16; off <<= 1) {
                s1 += __shfl_xor(s1, off, 64);
                s2 += __shfl_xor(s2, off, 64);
            }
            float mean = s1 * (1.f / 64.f);
            float var = s2 * (1.f / 64.f) - mean * mean;
            float rstd = rsqrtf(var + 1e-5f);
            #pragma unroll
            for (int j = 0; j < 4; j++)
                out[(slab + j * 16 + fr) * 24 + t] =
                    (v[j] - mean) * rstd * lnw_v[j] + lnb_v[j];
        }
    }
}

// ---------------------------------------------------------------------------
extern "C" void kernel_launch(void* const* d_in, const int* in_sizes, int n_in,
                              void* d_out, int out_size, void* d_ws, size_t ws_size,
                              hipStream_t stream)
{
    const float* x     = (const float*)d_in[0];
    const float* cheb  = (const float*)d_in[1];
    const float* W1    = (const float*)d_in[2];
    const float* W2    = (const float*)d_in[3];
    const float* W3    = (const float*)d_in[4];
    const float* bs    = (const float*)d_in[5];
    const float* Vs    = (const float*)d_in[6];
    const float* U1    = (const float*)d_in[7];
    const float* U2    = (const float*)d_in[8];
    const float* U3    = (const float*)d_in[9];
    const float* be    = (const float*)d_in[10];
    const float* Ve    = (const float*)d_in[11];
    const float* Theta = (const float*)d_in[12];
    const float* cw    = (const float*)d_in[13];
    const float* cbp   = (const float*)d_in[14];
    const float* lnw   = (const float*)d_in[15];
    const float* lnb   = (const float*)d_in[16];
    float* out = (float*)d_out;
    float* ws  = (float*)d_ws;

    // workspace layout (f32-slot offsets); peak ~126 MB
    unsigned short* Vs_bf   = (unsigned short*)(ws);              // 262144 u16
    unsigned short* cheb_bf = (unsigned short*)(ws + 131072);     // 786432 u16
    float*  lhs  = ws + 524288;
    float*  rhs  = ws + 917504;
    float*  part = ws + 1310720;
    float*  Ebuf = ws + 2097152;
    float*  S0   = ws + 2115584;                                  // 8.4M f32 (also XTn, later W2g)
    unsigned short* XTn = (unsigned short*)S0;
    unsigned short* W2g = (unsigned short*)S0;                    // after GEMM loop
    unsigned short* Pt  = (unsigned short*)(ws + 10504192);
    unsigned short* St  = Pt;
    unsigned short* Wk  = (unsigned short*)(ws + 14698496);
    unsigned short* XTt = (unsigned short*)(ws + 18892800);       // 25.2M u16
    unsigned short* hT  = XTt;                                    // reuse after GEMM loop

    const long long NN2 = (long long)cN * cN;
    const long long NJT = (long long)cFT * cN;
    const long long NFT = (long long)cN * cFT;

    k_convert<<<1024, 256, 0, stream>>>(Vs, Vs_bf, 262144);
    k_convert<<<3072, 256, 0, stream>>>(cheb, cheb_bf, 786432);

    k_spatial_lr<<<cB * cN, 64, 0, stream>>>(x, W1, W2, W3, lhs, rhs);
    k_product_t<<<dim3(32, 32, cB), dim3(16, 16), 0, stream>>>(lhs, rhs, bs, Pt);
    k_mfma_gemm<0><<<dim3(4, 4, cB), 256, 0, stream>>>(
        Vs_bf, 512, 0LL, Pt, 512, NN2, S0, 512, NN2, 512, 0, 0);
    k_softmax512<<<cB * cN, 256, 0, stream>>>(S0);
    k_transpose_S<<<dim3(8, 8, cB), 256, 0, stream>>>(S0, St);

    for (int k = 0; k < cK; k++) {
        for (int hf = 0; hf < 2; hf++) {
            k_xtheta_bf<<<cB * 256, 256, 0, stream>>>(x, Theta, k, hf, XTn);
            k_transpose_xt<<<dim3(4, 24, cB), 256, 0, stream>>>(XTn, hf, XTt);
        }
        k_mfma_gemm<1><<<dim3(4, 4, cB), 256, 0, stream>>>(
            cheb_bf + (size_t)k * NN2, 512, 0LL, St, 512, NN2,
            Wk, 512, NN2, 512, 0, 0);
        k_mfma_gemm<0><<<dim3(12, 4, cB), 256, 0, stream>>>(
            Wk, 512, NN2, XTt, 512, NJT, out, 1536, NFT, 512,
            (k > 0) ? 1 : 0, (k == 2) ? 1 : 0);
    }

    // temporal attention (reads h = out, pre-mixing)
    k_hU1_part<<<dim3(cB, 16), 256, 0, stream>>>(out, U1, part);
    k_rhs_t<<<cB * cN, 64, 0, stream>>>(out, U3, rhs);
    k_lhs_t<<<dim3(cB, 4), 256, 0, stream>>>(part, U2, lhs);
    k_E<<<cB, 576, 0, stream>>>(lhs, rhs, be, Ve, Ebuf);

    // weight prep (S0/XTn region is dead now)
    k_wprep<<<48, 256, 0, stream>>>(cw, W2g);

    // temporal mixing -> hT (bf16, [t,f] layout), then MFMA conv + LN -> out
    k_tmix_t<<<cB * cN, 256, 0, stream>>>(out, Ebuf, hT);
    k_convmfma<<<2048, 256, 0, stream>>>(hT, x, W2g, cbp, lnw, lnb, out);
}

// Round 5
// 1288.096 us; speedup vs baseline: 2.5081x; 1.1548x over previous
//
#include <hip/hip_runtime.h>

// Problem constants
constexpr int cB = 32, cN = 512, cC = 64, cT = 24, cK = 3, cF = 64;
constexpr int cCT = cC * cT;   // 1536
constexpr int cFT = cF * cT;   // 1536

typedef __attribute__((ext_vector_type(8))) short s16x8;            // MFMA bf16 frag
typedef __attribute__((ext_vector_type(8))) unsigned short u16x8;   // 16B load/store
typedef __attribute__((ext_vector_type(4))) float f32x4;            // MFMA acc

__device__ inline unsigned short f2bf(float f) {
    union { float f; unsigned int u; } v; v.f = f;
    unsigned int r = v.u + 0x7FFFu + ((v.u >> 16) & 1u);
    return (unsigned short)(r >> 16);
}

// ---------------------------------------------------------------------------
__global__ __launch_bounds__(64) void k_spatial_lr(
    const float* __restrict__ x, const float* __restrict__ W1,
    const float* __restrict__ W2, const float* __restrict__ W3,
    float* __restrict__ lhs, float* __restrict__ rhs)
{
    int bn = blockIdx.x;
    int tid = threadIdx.x;
    __shared__ float xs[64][25];
    __shared__ float a_sh[64];
    const float* xp = x + (size_t)bn * cCT;
    for (int i = tid; i < cCT; i += 64) xs[i / cT][i % cT] = xp[i];
    __syncthreads();
    float s = 0.f;
    #pragma unroll
    for (int t = 0; t < cT; t++) s += xs[tid][t] * W1[t];
    a_sh[tid] = s;
    __syncthreads();
    if (tid < cT) {
        float l = 0.f, r = 0.f;
        for (int c = 0; c < cC; c++) {
            l += a_sh[c] * W2[c * cT + tid];
            r += xs[c][tid] * W3[c];
        }
        lhs[(size_t)bn * cT + tid] = l;
        rhs[(size_t)bn * cT + tid] = r;
    }
}

// ---------------------------------------------------------------------------
// Pt[b,n,m] = bf16(sigmoid(sum_t lhs[b,m,t]*rhs[b,n,t] + bs[m,n]))  (transposed)
__global__ __launch_bounds__(256) void k_product_t(
    const float* __restrict__ lhs, const float* __restrict__ rhs,
    const float* __restrict__ bs, unsigned short* __restrict__ Pt)
{
    int b = blockIdx.z;
    int m0 = blockIdx.y * 16, n0 = blockIdx.x * 16;
    int tx = threadIdx.x, ty = threadIdx.y;
    int tid = ty * 16 + tx;
    __shared__ float L[16][25], R[16][25], bss[16][17];
    for (int i = tid; i < 16 * cT; i += 256) {
        int r = i / cT, c = i % cT;
        L[r][c] = lhs[((size_t)b * cN + m0 + r) * cT + c];
        R[r][c] = rhs[((size_t)b * cN + n0 + r) * cT + c];
    }
    bss[tid >> 4][tid & 15] = bs[(size_t)(m0 + (tid >> 4)) * cN + n0 + (tid & 15)];
    __syncthreads();
    float s = 0.f;
    #pragma unroll
    for (int t = 0; t < cT; t++) s += L[tx][t] * R[ty][t];
    s += bss[tx][ty];
    float sig = 1.f / (1.f + expf(-s));
    Pt[((size_t)b * cN + n0 + ty) * cN + m0 + tx] = f2bf(sig);
}

// ---------------------------------------------------------------------------
// Batched bf16 MFMA GEMM, 128x128 tile, BK=32, 4 waves, 16x16x32 MFMA.
// Segmented K: element kk lives in segment kk>>9 (512 per segment), at
// A + seg*segA + m*lda + (kk&511); same for B. Pass segA=segB=0 for K<=512.
template<int CM>
__global__ __launch_bounds__(256) void k_mfma_gemm(
    const unsigned short* __restrict__ A, int lda, long long aB, long long segA,
    const unsigned short* __restrict__ Bt, int ldb, long long bB, long long segB,
    void* __restrict__ Cv, int ldc, long long cBs,
    int K, int doAcc, int doRelu)
{
    __shared__ unsigned short As[128][40];
    __shared__ unsigned short Bs[128][40];
    int tid = threadIdx.x;
    int bn = blockIdx.x * 128;
    int bm = blockIdx.y * 128;
    int z  = blockIdx.z;
    const unsigned short* Ap = A  + (size_t)z * aB;
    const unsigned short* Bp = Bt + (size_t)z * bB;

    int lane = tid & 63, w = tid >> 6;
    int wm = (w >> 1) * 64, wn = (w & 1) * 64;
    int fr = lane & 15, kg = (lane >> 4) * 8;

    f32x4 acc[4][4] = {};

    int c0 = tid, c1 = tid + 256;
    int r0 = c0 >> 2, g0 = (c0 & 3) * 8;
    int r1 = c1 >> 2, g1 = (c1 & 3) * 8;

    for (int k0 = 0; k0 < K; k0 += 32) {
        int seg = k0 >> 9, off = k0 & 511;
        const unsigned short* Aseg = Ap + (size_t)seg * segA;
        const unsigned short* Bseg = Bp + (size_t)seg * segB;
        u16x8 a0 = *(const u16x8*)(Aseg + (size_t)(bm + r0) * lda + off + g0);
        u16x8 a1 = *(const u16x8*)(Aseg + (size_t)(bm + r1) * lda + off + g1);
        u16x8 b0 = *(const u16x8*)(Bseg + (size_t)(bn + r0) * ldb + off + g0);
        u16x8 b1 = *(const u16x8*)(Bseg + (size_t)(bn + r1) * ldb + off + g1);
        __syncthreads();
        *(u16x8*)&As[r0][g0] = a0;
        *(u16x8*)&As[r1][g1] = a1;
        *(u16x8*)&Bs[r0][g0] = b0;
        *(u16x8*)&Bs[r1][g1] = b1;
        __syncthreads();
        s16x8 af[4], bf[4];
        #pragma unroll
        for (int i = 0; i < 4; i++)
            af[i] = *(const s16x8*)&As[wm + i * 16 + fr][kg];
        #pragma unroll
        for (int j = 0; j < 4; j++)
            bf[j] = *(const s16x8*)&Bs[wn + j * 16 + fr][kg];
        #pragma unroll
        for (int i = 0; i < 4; i++)
            #pragma unroll
            for (int j = 0; j < 4; j++)
                acc[i][j] = __builtin_amdgcn_mfma_f32_16x16x32_bf16(
                    af[i], bf[j], acc[i][j], 0, 0, 0);
    }
    int rb = (lane >> 4) * 4;
    if (CM == 0) {
        float* Cp = (float*)Cv + (size_t)z * cBs;
        #pragma unroll
        for (int i = 0; i < 4; i++) {
            int row = bm + wm + i * 16 + rb;
            #pragma unroll
            for (int j = 0; j < 4; j++) {
                int col = bn + wn + j * 16 + fr;
                #pragma unroll
                for (int r = 0; r < 4; r++) {
                    size_t idx = (size_t)(row + r) * ldc + col;
                    float v = acc[i][j][r];
                    if (doAcc) v += Cp[idx];
                    if (doRelu) v = fmaxf(v, 0.f);
                    Cp[idx] = v;
                }
            }
        }
    } else {
        unsigned short* Cp = (unsigned short*)Cv + (size_t)z * cBs;
        #pragma unroll
        for (int i = 0; i < 4; i++) {
            int row = bm + wm + i * 16 + rb;
            #pragma unroll
            for (int j = 0; j < 4; j++) {
                int col = bn + wn + j * 16 + fr;
                #pragma unroll
                for (int r = 0; r < 4; r++)
                    Cp[(size_t)(row + r) * ldc + col] = f2bf(acc[i][j][r]);
            }
        }
    }
}

// ---------------------------------------------------------------------------
__global__ __launch_bounds__(256) void k_softmax512(float* __restrict__ S)
{
    int row = blockIdx.x;
    int tid = threadIdx.x;
    float* p = S + (size_t)row * cN;
    float v0 = p[tid], v1 = p[tid + 256];
    __shared__ float red[256];
    red[tid] = fmaxf(v0, v1);
    __syncthreads();
    for (int off = 128; off > 0; off >>= 1) {
        if (tid < off) red[tid] = fmaxf(red[tid], red[tid + off]);
        __syncthreads();
    }
    float mx = red[0];
    __syncthreads();
    float e0 = expf(v0 - mx), e1 = expf(v1 - mx);
    red[tid] = e0 + e1;
    __syncthreads();
    for (int off = 128; off > 0; off >>= 1) {
        if (tid < off) red[tid] += red[tid + off];
        __syncthreads();
    }
    float inv = 1.f / red[0];
    p[tid] = e0 * inv;
    p[tid + 256] = e1 * inv;
}

// ---------------------------------------------------------------------------
__global__ __launch_bounds__(256) void k_transpose_S(
    const float* __restrict__ S0, unsigned short* __restrict__ St)
{
    int b = blockIdx.z;
    int q0 = blockIdx.y * 64, n0 = blockIdx.x * 64;
    __shared__ float t[64][68];
    int tid = threadIdx.x;
    int r = tid >> 2, grp = (tid & 3) * 16;
    const float* ip = S0 + ((size_t)b * cN + q0 + r) * cN + n0 + grp;
    #pragma unroll
    for (int i = 0; i < 16; i += 4)
        *(float4*)&t[r][grp + i] = *(const float4*)(ip + i);
    __syncthreads();
    int nr = tid & 63, qg = (tid >> 6) * 16;
    unsigned short* op = St + ((size_t)b * cN + n0 + nr) * cN + q0 + qg;
    u16x8 v0, v1;
    #pragma unroll
    for (int i = 0; i < 8; i++) {
        v0[i] = f2bf(t[qg + i][nr]);
        v1[i] = f2bf(t[qg + 8 + i][nr]);
    }
    *(u16x8*)op = v0;
    *(u16x8*)(op + 8) = v1;
}

// ---------------------------------------------------------------------------
// XTn[z,n,j] = bf16( sum_c x[b,n,c,t]*Theta[k,c,f] ),  j=f*24+t, b=half*16+z
__global__ __launch_bounds__(256) void k_xtheta_bf(
    const float* __restrict__ x, const float* __restrict__ Theta,
    int k, int half, unsigned short* __restrict__ XTn)
{
    int idx = blockIdx.x;            // z*512 + n
    int z = idx >> 9, n = idx & 511;
    int b = half * 16 + z;
    int tid = threadIdx.x;
    __shared__ float xs[64][25];
    __shared__ float th[64 * 64];
    __shared__ float outs[64 * 25];
    const float* xp = x + ((size_t)b * cN + n) * cCT;
    for (int i = tid; i < cCT; i += 256) xs[i / cT][i % cT] = xp[i];
    const float* tp = Theta + (size_t)k * cC * cF;
    for (int i = tid; i < cC * cF; i += 256) th[i] = tp[i];
    __syncthreads();
    int f = tid & 63, g = tid >> 6;
    #pragma unroll
    for (int j = 0; j < 6; j++) {
        int t = g * 6 + j;
        float s = 0.f;
        #pragma unroll
        for (int c = 0; c < 64; c++) s += xs[c][t] * th[c * 64 + f];
        outs[f * 25 + t] = s;
    }
    __syncthreads();
    unsigned short* op = XTn + (size_t)idx * cFT;
    for (int i = tid; i < cFT; i += 256)
        op[i] = f2bf(outs[(i / cT) * 25 + i % cT]);
}

// ---------------------------------------------------------------------------
// XTt[z,j,n] = XTn[z,n,j]   (64x64 bf16 tiled transpose, per half/k slice)
__global__ __launch_bounds__(256) void k_transpose_xt(
    const unsigned short* __restrict__ XTn, unsigned short* __restrict__ XTt)
{
    int z = blockIdx.z;          // 0..15
    int n0 = blockIdx.x * 64;    // 0..448
    int j0 = blockIdx.y * 64;    // 0..1472
    __shared__ unsigned short t[64][72];
    int tid = threadIdx.x;
    int r = tid >> 2, grp = (tid & 3) * 16;
    const unsigned short* ip = XTn + ((size_t)z * 512 + n0 + r) * cFT + j0 + grp;
    *(u16x8*)&t[r][grp]     = *(const u16x8*)(ip);
    *(u16x8*)&t[r][grp + 8] = *(const u16x8*)(ip + 8);
    __syncthreads();
    int jr = tid & 63, ng = (tid >> 6) * 16;
    unsigned short* op = XTt + ((size_t)z * cFT + j0 + jr) * 512 + n0 + ng;
    u16x8 v0, v1;
    #pragma unroll
    for (int i = 0; i < 8; i++) {
        v0[i] = t[ng + i][jr];
        v1[i] = t[ng + 8 + i][jr];
    }
    *(u16x8*)op = v0;
    *(u16x8*)(op + 8) = v1;
}

// ---------------------------------------------------------------------------
__global__ void k_convert(const float* __restrict__ a,
                          unsigned short* __restrict__ o, int n)
{
    int i = blockIdx.x * 256 + threadIdx.x;
    if (i < n) o[i] = f2bf(a[i]);
}

// ---------------------------------------------------------------------------
// W2g[f][d*64+fi] = bf16(conv_w[f][fi][0][d])
__global__ void k_wprep(const float* __restrict__ cw,
                        unsigned short* __restrict__ W2g)
{
    int i = blockIdx.x * 256 + threadIdx.x;
    if (i < 64 * 192) {
        int f = i / 192, k = i % 192;
        int d = k >> 6, fi = k & 63;
        W2g[i] = f2bf(cw[f * 192 + fi * 3 + d]);
    }
}

// ---------------------------------------------------------------------------
__global__ __launch_bounds__(256) void k_hU1_part(
    const float* __restrict__ h, const float* __restrict__ U1,
    float* __restrict__ part)
{
    int b = blockIdx.x, nc = blockIdx.y;
    int tid = threadIdx.x;
    int f = tid & 63, q = tid >> 6;
    float acc[24];
    #pragma unroll
    for (int t = 0; t < 24; t++) acc[t] = 0.f;
    for (int n = nc * 32 + q; n < nc * 32 + 32; n += 4) {
        float u = U1[n];
        const float4* hp = (const float4*)(h + (((size_t)b * cN + n) * cF + f) * cT);
        #pragma unroll
        for (int v4 = 0; v4 < 6; v4++) {
            float4 hv = hp[v4];
            acc[v4 * 4 + 0] += u * hv.x;
            acc[v4 * 4 + 1] += u * hv.y;
            acc[v4 * 4 + 2] += u * hv.z;
            acc[v4 * 4 + 3] += u * hv.w;
        }
    }
    __shared__ float ps[4][64][25];
    #pragma unroll
    for (int t = 0; t < 24; t++) ps[q][f][t] = acc[t];
    __syncthreads();
    for (int i = tid; i < cFT; i += 256) {
        int f2 = i / cT, t2 = i % cT;
        float s = ps[0][f2][t2] + ps[1][f2][t2] + ps[2][f2][t2] + ps[3][f2][t2];
        part[(((size_t)b * 16 + nc) * cF + f2) * cT + t2] = s;
    }
}

// ---------------------------------------------------------------------------
__global__ __launch_bounds__(256) void k_lhs_t(
    const float* __restrict__ part, const float* __restrict__ U2,
    float* __restrict__ lhs_t)
{
    int b = blockIdx.x, ch = blockIdx.y;
    int tid = threadIdx.x;
    __shared__ float hu[1536];
    for (int i = tid; i < 1536; i += 256) {
        float s = 0.f;
        for (int nc = 0; nc < 16; nc++)
            s += part[((size_t)b * 16 + nc) * 1536 + i];
        hu[i] = s;
    }
    __syncthreads();
    int nn0 = ch * 128;
    for (int i = tid; i < cT * 128; i += 256) {
        int t = i / 128, nn = nn0 + (i % 128);
        float s = 0.f;
        #pragma unroll
        for (int f = 0; f < 64; f++) s += hu[f * cT + t] * U2[(size_t)f * cN + nn];
        lhs_t[((size_t)b * cT + t) * cN + nn] = s;
    }
}

// ---------------------------------------------------------------------------
__global__ __launch_bounds__(64) void k_rhs_t(
    const float* __restrict__ h, const float* __restrict__ U3,
    float* __restrict__ rhs_t)
{
    int bn = blockIdx.x;
    int f = threadIdx.x;
    __shared__ float sl[64][25];
    const float4* hp = (const float4*)(h + (size_t)bn * cFT + f * cT);
    float u = U3[f];
    #pragma unroll
    for (int v4 = 0; v4 < 6; v4++) {
        float4 hv = hp[v4];
        sl[f][v4 * 4 + 0] = u * hv.x;
        sl[f][v4 * 4 + 1] = u * hv.y;
        sl[f][v4 * 4 + 2] = u * hv.z;
        sl[f][v4 * 4 + 3] = u * hv.w;
    }
    __syncthreads();
    if (f < cT) {
        float s = 0.f;
        #pragma unroll
        for (int c = 0; c < 64; c++) s += sl[c][f];
        rhs_t[(size_t)bn * cT + f] = s;
    }
}

// ---------------------------------------------------------------------------
__global__ __launch_bounds__(576) void k_E(
    const float* __restrict__ lhs_t, const float* __restrict__ rhs_t,
    const float* __restrict__ be, const float* __restrict__ Ve,
    float* __restrict__ E)
{
    int b = blockIdx.x;
    int tid = threadIdx.x;
    int i = tid / 24, j = tid % 24;
    __shared__ float ps[24][25];
    __shared__ float er[24][25];
    __shared__ float mrow[24], srow[24];
    const float* lp = lhs_t + ((size_t)b * cT + i) * cN;
    const float* rp = rhs_t + (size_t)b * cN * cT;
    float s = 0.f;
    for (int n = 0; n < cN; n++) s += lp[n] * rp[n * cT + j];
    s += be[i * cT + j];
    ps[i][j] = 1.f / (1.f + expf(-s));
    __syncthreads();
    float e = 0.f;
    #pragma unroll
    for (int ss = 0; ss < cT; ss++) e += Ve[i * cT + ss] * ps[ss][j];
    er[i][j] = e;
    __syncthreads();
    if (j == 0) {
        float m = -1e30f;
        for (int r = 0; r < cT; r++) m = fmaxf(m, er[i][r]);
        float sm = 0.f;
        for (int r = 0; r < cT; r++) sm += expf(er[i][r] - m);
        mrow[i] = m;
        srow[i] = sm;
    }
    __syncthreads();
    E[(size_t)b * cT * cT + i * cT + j] = expf(er[i][j] - mrow[i]) / srow[i];
}

// ---------------------------------------------------------------------------
// temporal mixing, emits hT[b,n,t,f] in bf16 (h input unchanged)
__global__ __launch_bounds__(256) void k_tmix_t(
    const float* __restrict__ h, const float* __restrict__ E,
    unsigned short* __restrict__ hT)
{
    int bn = blockIdx.x;
    int b = bn >> 9;
    int tid = threadIdx.x;
    __shared__ float hs[64][25];
    __shared__ float Es[24][24];
    __shared__ float outs[24][65];
    const float* hp = h + (size_t)bn * cFT;
    for (int i = tid; i < cFT; i += 256) hs[i / cT][i % cT] = hp[i];
    for (int i = tid; i < 576; i += 256)
        Es[i / 24][i % 24] = E[(size_t)b * 576 + i];
    __syncthreads();
    int f = tid & 63, g = tid >> 6;
    #pragma unroll
    for (int j = 0; j < 6; j++) {
        int so = g * 6 + j;
        float s = 0.f;
        #pragma unroll
        for (int t = 0; t < cT; t++) s += hs[f][t] * Es[t][so];
        outs[so][f] = s;
    }
    __syncthreads();
    unsigned short* op = hT + (size_t)bn * cFT;
    for (int i = tid; i < cFT; i += 256)
        op[i] = f2bf(outs[i >> 6][i & 63]);
}

// ---------------------------------------------------------------------------
// MFMA conv(1,3) + bias + residual(x) + LayerNorm over F.
__global__ __launch_bounds__(256) void k_convmfma(
    const unsigned short* __restrict__ hT,   // [b,n,t,f] bf16
    const float* __restrict__ x,             // [b,n,c,t] f32
    const unsigned short* __restrict__ W2g,  // [f][192] bf16, k=(d*64+fi)
    const float* __restrict__ cb,
    const float* __restrict__ lnw, const float* __restrict__ lnb,
    float* __restrict__ out)                 // [b,n,f,t] f32
{
    __shared__ unsigned short Hs[8][26][72];
    __shared__ unsigned short Ws[64][200];
    int tid = threadIdx.x;
    int blk = blockIdx.x;
    int b = blk >> 6;
    int n0 = (blk & 63) * 8;
    const unsigned short* hp = hT + ((size_t)b * cN + n0) * cFT;

    #pragma unroll
    for (int it = 0; it < 6; it++) {
        int v = tid + it * 256;
        int s = v / 192;
        int r = v % 192;
        int t = r >> 3, f0 = (r & 7) * 8;
        u16x8 val = *(const u16x8*)(hp + (size_t)s * cFT + t * 64 + f0);
        *(u16x8*)&Hs[s][1 + t][f0] = val;
    }
    if (tid < 144) {
        int s = tid / 18, rm = tid % 18;
        int side = rm / 9, c8 = (rm % 9) * 8;
        u16x8 z = {};
        *(u16x8*)&Hs[s][side * 25][c8] = z;
    }
    #pragma unroll
    for (int it = 0; it < 48; it++) {
        int i = tid + it * 256;
        Ws[i / 192][i % 192] = W2g[i];
    }
    __syncthreads();

    int lane = tid & 63, w = tid >> 6;
    int fr = lane & 15, kgrp = lane >> 4;
    f32x4 acc[3][4] = {};

    int sA[3], tA[3];
    #pragma unroll
    for (int mi = 0; mi < 3; mi++) {
        int row = (w * 3 + mi) * 16 + fr;
        sA[mi] = row / 24; tA[mi] = row % 24;
    }
    #pragma unroll
    for (int ks = 0; ks < 6; ks++) {
        int d = ks >> 1;
        int fi0 = (ks & 1) * 32 + kgrp * 8;
        s16x8 bf[4];
        #pragma unroll
        for (int j = 0; j < 4; j++)
            bf[j] = *(const s16x8*)&Ws[j * 16 + fr][ks * 32 + kgrp * 8];
        #pragma unroll
        for (int mi = 0; mi < 3; mi++) {
            s16x8 af = *(const s16x8*)&Hs[sA[mi]][tA[mi] + d][fi0];
            #pragma unroll
            for (int j = 0; j < 4; j++)
                acc[mi][j] = __builtin_amdgcn_mfma_f32_16x16x32_bf16(
                    af, bf[j], acc[mi][j], 0, 0, 0);
        }
    }

    float lnw_v[4], lnb_v[4], cb_v[4];
    #pragma unroll
    for (int j = 0; j < 4; j++) {
        int f = j * 16 + fr;
        lnw_v[j] = lnw[f]; lnb_v[j] = lnb[f]; cb_v[j] = cb[f];
    }
    #pragma unroll
    for (int mi = 0; mi < 3; mi++) {
        int rowbase = (w * 3 + mi) * 16 + kgrp * 4;
        #pragma unroll
        for (int r = 0; r < 4; r++) {
            int row = rowbase + r;
            int s = row / 24, t = row % 24;
            size_t slab = ((size_t)b * cN + n0 + s) * 64;
            float v[4], s1 = 0.f, s2 = 0.f;
            #pragma unroll
            for (int j = 0; j < 4; j++) {
                float xres = x[(slab + j * 16 + fr) * 24 + t];
                v[j] = acc[mi][j][r] + cb_v[j] + xres;
                s1 += v[j];
                s2 += v[j] * v[j];
            }
            #pragma unroll
            for (int off = 1; off < 16; off <<= 1) {
                s1 += __shfl_xor(s1, off, 64);
                s2 += __shfl_xor(s2, off, 64);
            }
            float mean = s1 * (1.f / 64.f);
            float var = s2 * (1.f / 64.f) - mean * mean;
            float rstd = rsqrtf(var + 1e-5f);
            #pragma unroll
            for (int j = 0; j < 4; j++)
                out[(slab + j * 16 + fr) * 24 + t] =
                    (v[j] - mean) * rstd * lnw_v[j] + lnb_v[j];
        }
    }
}

// ---------------------------------------------------------------------------
extern "C" void kernel_launch(void* const* d_in, const int* in_sizes, int n_in,
                              void* d_out, int out_size, void* d_ws, size_t ws_size,
                              hipStream_t stream)
{
    const float* x     = (const float*)d_in[0];
    const float* cheb  = (const float*)d_in[1];
    const float* W1    = (const float*)d_in[2];
    const float* W2    = (const float*)d_in[3];
    const float* W3    = (const float*)d_in[4];
    const float* bs    = (const float*)d_in[5];
    const float* Vs    = (const float*)d_in[6];
    const float* U1    = (const float*)d_in[7];
    const float* U2    = (const float*)d_in[8];
    const float* U3    = (const float*)d_in[9];
    const float* be    = (const float*)d_in[10];
    const float* Ve    = (const float*)d_in[11];
    const float* Theta = (const float*)d_in[12];
    const float* cw    = (const float*)d_in[13];
    const float* cbp   = (const float*)d_in[14];
    const float* lnw   = (const float*)d_in[15];
    const float* lnb   = (const float*)d_in[16];
    float* out = (float*)d_out;
    float* ws  = (float*)d_ws;

    // workspace layout (offsets in f32 slots); peak ~151 MB
    unsigned short* Vs_bf   = (unsigned short*)(ws);              // 131072 slots
    unsigned short* cheb_bf = (unsigned short*)(ws + 131072);     // 393216
    float*  lhs  = ws + 524288;     // 393216 (also lhs_t)
    float*  rhs  = ws + 917504;     // 393216 (also rhs_t)
    float*  part = ws + 1310720;    // 786432
    float*  Ebuf = ws + 2097152;    // 18432
    unsigned short* W2g = (unsigned short*)(ws + 2115584);        // 6144 slots
    unsigned short* St  = (unsigned short*)(ws + 2121728);        // 4194304 slots (32 b)
    unsigned short* Wk  = (unsigned short*)(ws + 6316032);        // [3][16][512][512] 6291456 slots
    unsigned short* XTt = (unsigned short*)(ws + 12607488);       // [3][16][1536][512] 18874368 slots
    unsigned short* Pt  = (unsigned short*)(ws + 12607488);       // overlay (dead before XTt)
    float*          S0  = ws + 16801792;                          // 8388608 f32 (dead before XTt)
    unsigned short* XTn = (unsigned short*)(ws + 31481856);       // [16*512][1536] 6291456 slots
    unsigned short* hT  = XTt;                                    // reuse after GEMM loop

    const long long NN2 = (long long)cN * cN;        // 262144
    const long long NFT = (long long)cN * cFT;       // 786432
    const long long segW = 16LL * NN2;               // Wk k-segment (u16 elems)
    const long long segX = 16LL * 1536 * 512;        // XTt k-segment

    k_convert<<<1024, 256, 0, stream>>>(Vs, Vs_bf, 262144);
    k_convert<<<3072, 256, 0, stream>>>(cheb, cheb_bf, 786432);
    k_wprep<<<48, 256, 0, stream>>>(cw, W2g);

    // spatial attention
    k_spatial_lr<<<cB * cN, 64, 0, stream>>>(x, W1, W2, W3, lhs, rhs);
    k_product_t<<<dim3(32, 32, cB), dim3(16, 16), 0, stream>>>(lhs, rhs, bs, Pt);
    k_mfma_gemm<0><<<dim3(4, 4, cB), 256, 0, stream>>>(
        Vs_bf, 512, 0LL, 0LL, Pt, 512, NN2, 0LL, S0, 512, NN2, 512, 0, 0);
    k_softmax512<<<cB * cN, 256, 0, stream>>>(S0);
    k_transpose_S<<<dim3(8, 8, cB), 256, 0, stream>>>(S0, St);

    // Cheb conv, batch-halved with fused-K final GEMM
    for (int half = 0; half < 2; half++) {
        for (int k = 0; k < cK; k++) {
            k_xtheta_bf<<<16 * 512, 256, 0, stream>>>(x, Theta, k, half, XTn);
            k_transpose_xt<<<dim3(8, 24, 16), 256, 0, stream>>>(
                XTn, XTt + (size_t)k * segX);
            // W_k = cheb_k @ S  (z local 0..15)
            k_mfma_gemm<1><<<dim3(4, 4, 16), 256, 0, stream>>>(
                cheb_bf + (size_t)k * NN2, 512, 0LL, 0LL,
                St + (size_t)half * 16 * NN2, 512, NN2, 0LL,
                Wk + (size_t)k * segW, 512, NN2, 512, 0, 0);
        }
        // h_half = relu( sum_k W_k @ XT_k )  — one pass, K=1536 segmented
        k_mfma_gemm<0><<<dim3(12, 4, 16), 256, 0, stream>>>(
            Wk, 512, NN2, segW, XTt, 512, 786432LL, segX,
            out + (size_t)half * 16 * NFT, 1536, NFT, 1536, 0, 1);
    }

    // temporal attention (reads h = out, pre-mixing)
    k_hU1_part<<<dim3(cB, 16), 256, 0, stream>>>(out, U1, part);
    k_rhs_t<<<cB * cN, 64, 0, stream>>>(out, U3, rhs);
    k_lhs_t<<<dim3(cB, 4), 256, 0, stream>>>(part, U2, lhs);
    k_E<<<cB, 576, 0, stream>>>(lhs, rhs, be, Ve, Ebuf);

    // temporal mixing -> hT (bf16, [t,f] layout), then MFMA conv + LN -> out
    k_tmix_t<<<cB * cN, 256, 0, stream>>>(out, Ebuf, hT);
    k_convmfma<<<2048, 256, 0, stream>>>(hT, x, W2g, cbp, lnw, lnb, out);
}

// Round 8
// 702.996 us; speedup vs baseline: 4.5955x; 1.8323x over previous
//
#include <hip/hip_runtime.h>

// Problem constants
constexpr int cB = 32, cN = 512, cC = 64, cT = 24, cK = 3, cF = 64;
constexpr int cCT = cC * cT;   // 1536
constexpr int cFT = cF * cT;   // 1536

typedef __attribute__((ext_vector_type(8))) short s16x8;            // MFMA bf16 frag
typedef __attribute__((ext_vector_type(8))) unsigned short u16x8;   // 16B load/store
typedef __attribute__((ext_vector_type(4))) float f32x4;            // MFMA acc

__device__ inline unsigned short f2bf(float f) {
    union { float f; unsigned int u; } v; v.f = f;
    unsigned int r = v.u + 0x7FFFu + ((v.u >> 16) & 1u);
    return (unsigned short)(r >> 16);
}

// ---------------------------------------------------------------------------
__global__ __launch_bounds__(64) void k_spatial_lr(
    const float* __restrict__ x, const float* __restrict__ W1,
    const float* __restrict__ W2, const float* __restrict__ W3,
    float* __restrict__ lhs, float* __restrict__ rhs)
{
    int bn = blockIdx.x;
    int tid = threadIdx.x;
    __shared__ float xs[64][25];
    __shared__ float a_sh[64];
    const float* xp = x + (size_t)bn * cCT;
    for (int i = tid; i < cCT; i += 64) xs[i / cT][i % cT] = xp[i];
    __syncthreads();
    float s = 0.f;
    #pragma unroll
    for (int t = 0; t < cT; t++) s += xs[tid][t] * W1[t];
    a_sh[tid] = s;
    __syncthreads();
    if (tid < cT) {
        float l = 0.f, r = 0.f;
        for (int c = 0; c < cC; c++) {
            l += a_sh[c] * W2[c * cT + tid];
            r += xs[c][tid] * W3[c];
        }
        lhs[(size_t)bn * cT + tid] = l;
        rhs[(size_t)bn * cT + tid] = r;
    }
}

// ---------------------------------------------------------------------------
// Pt[b,n,m] = bf16(sigmoid(sum_t lhs[b,m,t]*rhs[b,n,t] + bs[m,n]))  (transposed)
__global__ __launch_bounds__(256) void k_product_t(
    const float* __restrict__ lhs, const float* __restrict__ rhs,
    const float* __restrict__ bs, unsigned short* __restrict__ Pt)
{
    int b = blockIdx.z;
    int m0 = blockIdx.y * 16, n0 = blockIdx.x * 16;
    int tx = threadIdx.x, ty = threadIdx.y;
    int tid = ty * 16 + tx;
    __shared__ float L[16][25], R[16][25], bss[16][17];
    for (int i = tid; i < 16 * cT; i += 256) {
        int r = i / cT, c = i % cT;
        L[r][c] = lhs[((size_t)b * cN + m0 + r) * cT + c];
        R[r][c] = rhs[((size_t)b * cN + n0 + r) * cT + c];
    }
    bss[tid >> 4][tid & 15] = bs[(size_t)(m0 + (tid >> 4)) * cN + n0 + (tid & 15)];
    __syncthreads();
    float s = 0.f;
    #pragma unroll
    for (int t = 0; t < cT; t++) s += L[tx][t] * R[ty][t];
    s += bss[tx][ty];
    float sig = 1.f / (1.f + expf(-s));
    Pt[((size_t)b * cN + n0 + ty) * cN + m0 + tx] = f2bf(sig);
}

// ---------------------------------------------------------------------------
// Batched bf16 MFMA GEMM, 128x128 tile, BK=32, 4 waves, 16x16x32 MFMA.
// Segmented K (512 per segment). Pass segA=segB=0 for K<=512.
template<int CM>
__global__ __launch_bounds__(256) void k_mfma_gemm(
    const unsigned short* __restrict__ A, int lda, long long aB, long long segA,
    const unsigned short* __restrict__ Bt, int ldb, long long bB, long long segB,
    void* __restrict__ Cv, int ldc, long long cBs,
    int K, int doAcc, int doRelu)
{
    __shared__ unsigned short As[128][40];
    __shared__ unsigned short Bs[128][40];
    int tid = threadIdx.x;
    int bn = blockIdx.x * 128;
    int bm = blockIdx.y * 128;
    int z  = blockIdx.z;
    const unsigned short* Ap = A  + (size_t)z * aB;
    const unsigned short* Bp = Bt + (size_t)z * bB;

    int lane = tid & 63, w = tid >> 6;
    int wm = (w >> 1) * 64, wn = (w & 1) * 64;
    int fr = lane & 15, kg = (lane >> 4) * 8;

    f32x4 acc[4][4] = {};

    int c0 = tid, c1 = tid + 256;
    int r0 = c0 >> 2, g0 = (c0 & 3) * 8;
    int r1 = c1 >> 2, g1 = (c1 & 3) * 8;

    for (int k0 = 0; k0 < K; k0 += 32) {
        int seg = k0 >> 9, off = k0 & 511;
        const unsigned short* Aseg = Ap + (size_t)seg * segA;
        const unsigned short* Bseg = Bp + (size_t)seg * segB;
        u16x8 a0 = *(const u16x8*)(Aseg + (size_t)(bm + r0) * lda + off + g0);
        u16x8 a1 = *(const u16x8*)(Aseg + (size_t)(bm + r1) * lda + off + g1);
        u16x8 b0 = *(const u16x8*)(Bseg + (size_t)(bn + r0) * ldb + off + g0);
        u16x8 b1 = *(const u16x8*)(Bseg + (size_t)(bn + r1) * ldb + off + g1);
        __syncthreads();
        *(u16x8*)&As[r0][g0] = a0;
        *(u16x8*)&As[r1][g1] = a1;
        *(u16x8*)&Bs[r0][g0] = b0;
        *(u16x8*)&Bs[r1][g1] = b1;
        __syncthreads();
        s16x8 af[4], bf[4];
        #pragma unroll
        for (int i = 0; i < 4; i++)
            af[i] = *(const s16x8*)&As[wm + i * 16 + fr][kg];
        #pragma unroll
        for (int j = 0; j < 4; j++)
            bf[j] = *(const s16x8*)&Bs[wn + j * 16 + fr][kg];
        #pragma unroll
        for (int i = 0; i < 4; i++)
            #pragma unroll
            for (int j = 0; j < 4; j++)
                acc[i][j] = __builtin_amdgcn_mfma_f32_16x16x32_bf16(
                    af[i], bf[j], acc[i][j], 0, 0, 0);
    }
    int rb = (lane >> 4) * 4;
    if (CM == 0) {
        float* Cp = (float*)Cv + (size_t)z * cBs;
        #pragma unroll
        for (int i = 0; i < 4; i++) {
            int row = bm + wm + i * 16 + rb;
            #pragma unroll
            for (int j = 0; j < 4; j++) {
                int col = bn + wn + j * 16 + fr;
                #pragma unroll
                for (int r = 0; r < 4; r++) {
                    size_t idx = (size_t)(row + r) * ldc + col;
                    float v = acc[i][j][r];
                    if (doAcc) v += Cp[idx];
                    if (doRelu) v = fmaxf(v, 0.f);
                    Cp[idx] = v;
                }
            }
        }
    } else {
        unsigned short* Cp = (unsigned short*)Cv + (size_t)z * cBs;
        #pragma unroll
        for (int i = 0; i < 4; i++) {
            int row = bm + wm + i * 16 + rb;
            #pragma unroll
            for (int j = 0; j < 4; j++) {
                int col = bn + wn + j * 16 + fr;
                #pragma unroll
                for (int r = 0; r < 4; r++)
                    Cp[(size_t)(row + r) * ldc + col] = f2bf(acc[i][j][r]);
            }
        }
    }
}

// ---------------------------------------------------------------------------
__global__ __launch_bounds__(256) void k_softmax512(float* __restrict__ S)
{
    int row = blockIdx.x;
    int tid = threadIdx.x;
    float* p = S + (size_t)row * cN;
    float v0 = p[tid], v1 = p[tid + 256];
    __shared__ float red[256];
    red[tid] = fmaxf(v0, v1);
    __syncthreads();
    for (int off = 128; off > 0; off >>= 1) {
        if (tid < off) red[tid] = fmaxf(red[tid], red[tid + off]);
        __syncthreads();
    }
    float mx = red[0];
    __syncthreads();
    float e0 = expf(v0 - mx), e1 = expf(v1 - mx);
    red[tid] = e0 + e1;
    __syncthreads();
    for (int off = 128; off > 0; off >>= 1) {
        if (tid < off) red[tid] += red[tid + off];
        __syncthreads();
    }
    float inv = 1.f / red[0];
    p[tid] = e0 * inv;
    p[tid + 256] = e1 * inv;
}

// ---------------------------------------------------------------------------
__global__ __launch_bounds__(256) void k_transpose_S(
    const float* __restrict__ S0, unsigned short* __restrict__ St)
{
    int b = blockIdx.z;
    int q0 = blockIdx.y * 64, n0 = blockIdx.x * 64;
    __shared__ float t[64][68];
    int tid = threadIdx.x;
    int r = tid >> 2, grp = (tid & 3) * 16;
    const float* ip = S0 + ((size_t)b * cN + q0 + r) * cN + n0 + grp;
    #pragma unroll
    for (int i = 0; i < 16; i += 4)
        *(float4*)&t[r][grp + i] = *(const float4*)(ip + i);
    __syncthreads();
    int nr = tid & 63, qg = (tid >> 6) * 16;
    unsigned short* op = St + ((size_t)b * cN + n0 + nr) * cN + q0 + qg;
    u16x8 v0, v1;
    #pragma unroll
    for (int i = 0; i < 8; i++) {
        v0[i] = f2bf(t[qg + i][nr]);
        v1[i] = f2bf(t[qg + 8 + i][nr]);
    }
    *(u16x8*)op = v0;
    *(u16x8*)(op + 8) = v1;
}

// ---------------------------------------------------------------------------
// xT2[z][t][n][c] = bf16(x[half*16+z][n][c][t])   (one pass per half)
__global__ __launch_bounds__(64) void k_xtrans_half(
    const float* __restrict__ x, int half, unsigned short* __restrict__ xT2)
{
    int idx = blockIdx.x;            // z*512 + n
    int z = idx >> 9, n = idx & 511;
    int b = half * 16 + z;
    int tid = threadIdx.x;
    __shared__ float xs[64][25];
    const float* xp = x + (size_t)(b * (size_t)cN + n) * cCT;
    for (int i = tid; i < cCT; i += 64) xs[i / cT][i % cT] = xp[i];
    __syncthreads();
    unsigned short* op = xT2 + (size_t)z * 786432 + (size_t)n * 64;
    for (int i = tid; i < cCT; i += 64) {
        int t = i >> 6, c = i & 63;
        op[(size_t)t * 32768 + c] = f2bf(xs[c][t]);
    }
}

// ---------------------------------------------------------------------------
// XT via MFMA, direct write to XTt[k][z][f*24+t][n].
// Block = (n-tile 128, t, z); loops k=0..2. A = xT2[z][t][n0..][c], B = ThT[k][f][c].
__global__ __launch_bounds__(256) void k_xtheta_mfma(
    const unsigned short* __restrict__ xT2,   // [z][t][n][c]
    const unsigned short* __restrict__ ThT,   // [k][f][c]
    unsigned short* __restrict__ XTt,         // [k][z][f*24+t][n]
    long long segX)
{
    __shared__ unsigned short As[128][72];
    __shared__ unsigned short Ths[64][72];
    __shared__ unsigned short Cs[64][136];
    int tid = threadIdx.x;
    int n0 = blockIdx.x * 128;
    int t  = blockIdx.y;
    int z  = blockIdx.z;

    // stage A-tile: 128 rows(n) x 64 c
    const unsigned short* ap = xT2 + (size_t)z * 786432 + (size_t)t * 32768 + n0 * 64;
    #pragma unroll
    for (int it = 0; it < 4; it++) {
        int v = tid + it * 256;
        int row = v >> 3, c8 = (v & 7) * 8;
        *(u16x8*)&As[row][c8] = *(const u16x8*)(ap + row * 64 + c8);
    }

    int lane = tid & 63, w = tid >> 6;
    int fr = lane & 15, kg = (lane >> 4) * 8;
    int rb = (lane >> 4) * 4;

    for (int k = 0; k < cK; k++) {
        __syncthreads();   // prev Cs/Ths reads + (k=0) A-stage done
        // stage ThT[k]: 64 rows(f) x 64 c  = 512 vec8, 2 per thread
        #pragma unroll
        for (int it = 0; it < 2; it++) {
            int vi = tid + it * 256;         // 0..511
            int row = vi >> 3, c8 = (vi & 7) * 8;
            *(u16x8*)&Ths[row][c8] =
                *(const u16x8*)(ThT + (size_t)k * 4096 + row * 64 + c8);
        }
        __syncthreads();
        f32x4 acc[2][4] = {};
        #pragma unroll
        for (int ks = 0; ks < 2; ks++) {
            s16x8 af[2], bf[4];
            #pragma unroll
            for (int i = 0; i < 2; i++)
                af[i] = *(const s16x8*)&As[w * 32 + i * 16 + fr][ks * 32 + kg];
            #pragma unroll
            for (int j = 0; j < 4; j++)
                bf[j] = *(const s16x8*)&Ths[j * 16 + fr][ks * 32 + kg];
            #pragma unroll
            for (int i = 0; i < 2; i++)
                #pragma unroll
                for (int j = 0; j < 4; j++)
                    acc[i][j] = __builtin_amdgcn_mfma_f32_16x16x32_bf16(
                        af[i], bf[j], acc[i][j], 0, 0, 0);
        }
        // write C frags to LDS bounce: Cs[f][n_local]
        #pragma unroll
        for (int i = 0; i < 2; i++) {
            int rowb = w * 32 + i * 16 + rb;
            #pragma unroll
            for (int j = 0; j < 4; j++) {
                int f = j * 16 + fr;
                #pragma unroll
                for (int r = 0; r < 4; r++)
                    Cs[f][rowb + r] = f2bf(acc[i][j][r]);
            }
        }
        __syncthreads();
        // store Cs -> XTt[k][z][(f*24+t)][n0..n0+127]
        unsigned short* op = XTt + (size_t)k * segX + (size_t)z * 786432 + n0;
        #pragma unroll
        for (int it = 0; it < 4; it++) {
            int v = tid + it * 256;
            int f = v >> 4, n8 = (v & 15) * 8;
            *(u16x8*)(op + (size_t)(f * 24 + t) * 512 + n8) = *(const u16x8*)&Cs[f][n8];
        }
    }
}

// ---------------------------------------------------------------------------
__global__ void k_convert(const float* __restrict__ a,
                          unsigned short* __restrict__ o, int n)
{
    int i = blockIdx.x * 256 + threadIdx.x;
    if (i < n) o[i] = f2bf(a[i]);
}

// ---------------------------------------------------------------------------
// W2g[f][d*64+fi] = bf16(conv_w[f][fi][0][d])
__global__ void k_wprep(const float* __restrict__ cw,
                        unsigned short* __restrict__ W2g)
{
    int i = blockIdx.x * 256 + threadIdx.x;
    if (i < 64 * 192) {
        int f = i / 192, k = i % 192;
        int d = k >> 6, fi = k & 63;
        W2g[i] = f2bf(cw[f * 192 + fi * 3 + d]);
    }
}

// ---------------------------------------------------------------------------
// ThT[k][f][c] = bf16(Theta[k][c][f])
__global__ void k_thprep(const float* __restrict__ Theta,
                         unsigned short* __restrict__ ThT)
{
    int i = blockIdx.x * 256 + threadIdx.x;
    if (i < cK * 64 * 64) {
        int k = i >> 12, r = i & 4095;
        int f = r >> 6, c = r & 63;
        ThT[i] = f2bf(Theta[k * 4096 + c * 64 + f]);
    }
}

// ---------------------------------------------------------------------------
__global__ __launch_bounds__(256) void k_hU1_part(
    const float* __restrict__ h, const float* __restrict__ U1,
    float* __restrict__ part)
{
    int b = blockIdx.x, nc = blockIdx.y;
    int tid = threadIdx.x;
    int f = tid & 63, q = tid >> 6;
    float acc[24];
    #pragma unroll
    for (int t = 0; t < 24; t++) acc[t] = 0.f;
    for (int n = nc * 32 + q; n < nc * 32 + 32; n += 4) {
        float u = U1[n];
        const float4* hp = (const float4*)(h + (((size_t)b * cN + n) * cF + f) * cT);
        #pragma unroll
        for (int v4 = 0; v4 < 6; v4++) {
            float4 hv = hp[v4];
            acc[v4 * 4 + 0] += u * hv.x;
            acc[v4 * 4 + 1] += u * hv.y;
            acc[v4 * 4 + 2] += u * hv.z;
            acc[v4 * 4 + 3] += u * hv.w;
        }
    }
    __shared__ float ps[4][64][25];
    #pragma unroll
    for (int t = 0; t < 24; t++) ps[q][f][t] = acc[t];
    __syncthreads();
    for (int i = tid; i < cFT; i += 256) {
        int f2 = i / cT, t2 = i % cT;
        float s = ps[0][f2][t2] + ps[1][f2][t2] + ps[2][f2][t2] + ps[3][f2][t2];
        part[(((size_t)b * 16 + nc) * cF + f2) * cT + t2] = s;
    }
}

// ---------------------------------------------------------------------------
__global__ __launch_bounds__(256) void k_lhs_t(
    const float* __restrict__ part, const float* __restrict__ U2,
    float* __restrict__ lhs_t)
{
    int b = blockIdx.x, ch = blockIdx.y;
    int tid = threadIdx.x;
    __shared__ float hu[1536];
    for (int i = tid; i < 1536; i += 256) {
        float s = 0.f;
        for (int nc = 0; nc < 16; nc++)
            s += part[((size_t)b * 16 + nc) * 1536 + i];
        hu[i] = s;
    }
    __syncthreads();
    int nn0 = ch * 128;
    for (int i = tid; i < cT * 128; i += 256) {
        int t = i / 128, nn = nn0 + (i % 128);
        float s = 0.f;
        #pragma unroll
        for (int f = 0; f < 64; f++) s += hu[f * cT + t] * U2[(size_t)f * cN + nn];
        lhs_t[((size_t)b * cT + t) * cN + nn] = s;
    }
}

// ---------------------------------------------------------------------------
__global__ __launch_bounds__(64) void k_rhs_t(
    const float* __restrict__ h, const float* __restrict__ U3,
    float* __restrict__ rhs_t)
{
    int bn = blockIdx.x;
    int f = threadIdx.x;
    __shared__ float sl[64][25];
    const float4* hp = (const float4*)(h + (size_t)bn * cFT + f * cT);
    float u = U3[f];
    #pragma unroll
    for (int v4 = 0; v4 < 6; v4++) {
        float4 hv = hp[v4];
        sl[f][v4 * 4 + 0] = u * hv.x;
        sl[f][v4 * 4 + 1] = u * hv.y;
        sl[f][v4 * 4 + 2] = u * hv.z;
        sl[f][v4 * 4 + 3] = u * hv.w;
    }
    __syncthreads();
    if (f < cT) {
        float s = 0.f;
        #pragma unroll
        for (int c = 0; c < 64; c++) s += sl[c][f];
        rhs_t[(size_t)bn * cT + f] = s;
    }
}

// ---------------------------------------------------------------------------
__global__ __launch_bounds__(576) void k_E(
    const float* __restrict__ lhs_t, const float* __restrict__ rhs_t,
    const float* __restrict__ be, const float* __restrict__ Ve,
    float* __restrict__ E)
{
    int b = blockIdx.x;
    int tid = threadIdx.x;
    int i = tid / 24, j = tid % 24;
    __shared__ float ps[24][25];
    __shared__ float er[24][25];
    __shared__ float mrow[24], srow[24];
    const float* lp = lhs_t + ((size_t)b * cT + i) * cN;
    const float* rp = rhs_t + (size_t)b * cN * cT;
    float s = 0.f;
    for (int n = 0; n < cN; n++) s += lp[n] * rp[n * cT + j];
    s += be[i * cT + j];
    ps[i][j] = 1.f / (1.f + expf(-s));
    __syncthreads();
    float e = 0.f;
    #pragma unroll
    for (int ss = 0; ss < cT; ss++) e += Ve[i * cT + ss] * ps[ss][j];
    er[i][j] = e;
    __syncthreads();
    if (j == 0) {
        float m = -1e30f;
        for (int r = 0; r < cT; r++) m = fmaxf(m, er[i][r]);
        float sm = 0.f;
        for (int r = 0; r < cT; r++) sm += expf(er[i][r] - m);
        mrow[i] = m;
        srow[i] = sm;
    }
    __syncthreads();
    E[(size_t)b * cT * cT + i * cT + j] = expf(er[i][j] - mrow[i]) / srow[i];
}

// ---------------------------------------------------------------------------
// temporal mixing, emits hT[b,n,t,f] in bf16 (h input unchanged)
__global__ __launch_bounds__(256) void k_tmix_t(
    const float* __restrict__ h, const float* __restrict__ E,
    unsigned short* __restrict__ hT)
{
    int bn = blockIdx.x;
    int b = bn >> 9;
    int tid = threadIdx.x;
    __shared__ float hs[64][25];
    __shared__ float Es[24][24];
    __shared__ float outs[24][65];
    const float* hp = h + (size_t)bn * cFT;
    for (int i = tid; i < cFT; i += 256) hs[i / cT][i % cT] = hp[i];
    for (int i = tid; i < 576; i += 256)
        Es[i / 24][i % 24] = E[(size_t)b * 576 + i];
    __syncthreads();
    int f = tid & 63, g = tid >> 6;
    #pragma unroll
    for (int j = 0; j < 6; j++) {
        int so = g * 6 + j;
        float s = 0.f;
        #pragma unroll
        for (int t = 0; t < cT; t++) s += hs[f][t] * Es[t][so];
        outs[so][f] = s;
    }
    __syncthreads();
    unsigned short* op = hT + (size_t)bn * cFT;
    for (int i = tid; i < cFT; i += 256)
        op[i] = f2bf(outs[i >> 6][i & 63]);
}

// ---------------------------------------------------------------------------
// MFMA conv(1,3) + bias + residual(x) + LayerNorm over F.
__global__ __launch_bounds__(256) void k_convmfma(
    const unsigned short* __restrict__ hT,   // [b,n,t,f] bf16
    const float* __restrict__ x,             // [b,n,c,t] f32
    const unsigned short* __restrict__ W2g,  // [f][192] bf16, k=(d*64+fi)
    const float* __restrict__ cb,
    const float* __restrict__ lnw, const float* __restrict__ lnb,
    float* __restrict__ out)                 // [b,n,f,t] f32
{
    __shared__ unsigned short Hs[8][26][72];
    __shared__ unsigned short Ws[64][200];
    int tid = threadIdx.x;
    int blk = blockIdx.x;
    int b = blk >> 6;
    int n0 = (blk & 63) * 8;
    const unsigned short* hp = hT + ((size_t)b * cN + n0) * cFT;

    #pragma unroll
    for (int it = 0; it < 6; it++) {
        int v = tid + it * 256;
        int s = v / 192;
        int r = v % 192;
        int t = r >> 3, f0 = (r & 7) * 8;
        u16x8 val = *(const u16x8*)(hp + (size_t)s * cFT + t * 64 + f0);
        *(u16x8*)&Hs[s][1 + t][f0] = val;
    }
    if (tid < 144) {
        int s = tid / 18, rm = tid % 18;
        int side = rm / 9, c8 = (rm % 9) * 8;
        u16x8 z = {};
        *(u16x8*)&Hs[s][side * 25][c8] = z;
    }
    #pragma unroll
    for (int it = 0; it < 48; it++) {
        int i = tid + it * 256;
        Ws[i / 192][i % 192] = W2g[i];
    }
    __syncthreads();

    int lane = tid & 63, w = tid >> 6;
    int fr = lane & 15, kgrp = lane >> 4;
    f32x4 acc[3][4] = {};

    int sA[3], tA[3];
    #pragma unroll
    for (int mi = 0; mi < 3; mi++) {
        int row = (w * 3 + mi) * 16 + fr;
        sA[mi] = row / 24; tA[mi] = row % 24;
    }
    #pragma unroll
    for (int ks = 0; ks < 6; ks++) {
        int d = ks >> 1;
        int fi0 = (ks & 1) * 32 + kgrp * 8;
        s16x8 bf[4];
        #pragma unroll
        for (int j = 0; j < 4; j++)
            bf[j] = *(const s16x8*)&Ws[j * 16 + fr][ks * 32 + kgrp * 8];
        #pragma unroll
        for (int mi = 0; mi < 3; mi++) {
            s16x8 af = *(const s16x8*)&Hs[sA[mi]][tA[mi] + d][fi0];
            #pragma unroll
            for (int j = 0; j < 4; j++)
                acc[mi][j] = __builtin_amdgcn_mfma_f32_16x16x32_bf16(
                    af, bf[j], acc[mi][j], 0, 0, 0);
        }
    }

    float lnw_v[4], lnb_v[4], cb_v[4];
    #pragma unroll
    for (int j = 0; j < 4; j++) {
        int f = j * 16 + fr;
        lnw_v[j] = lnw[f]; lnb_v[j] = lnb[f]; cb_v[j] = cb[f];
    }
    #pragma unroll
    for (int mi = 0; mi < 3; mi++) {
        int rowbase = (w * 3 + mi) * 16 + kgrp * 4;
        #pragma unroll
        for (int r = 0; r < 4; r++) {
            int row = rowbase + r;
            int s = row / 24, t = row % 24;
            size_t slab = ((size_t)b * cN + n0 + s) * 64;
            float v[4], s1 = 0.f, s2 = 0.f;
            #pragma unroll
            for (int j = 0; j < 4; j++) {
                float xres = x[(slab + j * 16 + fr) * 24 + t];
                v[j] = acc[mi][j][r] + cb_v[j] + xres;
                s1 += v[j];
                s2 += v[j] * v[j];
            }
            #pragma unroll
            for (int off = 1; off < 16; off <<= 1) {
                s1 += __shfl_xor(s1, off, 64);
                s2 += __shfl_xor(s2, off, 64);
            }
            float mean = s1 * (1.f / 64.f);
            float var = s2 * (1.f / 64.f) - mean * mean;
            float rstd = rsqrtf(var + 1e-5f);
            #pragma unroll
            for (int j = 0; j < 4; j++)
                out[(slab + j * 16 + fr) * 24 + t] =
                    (v[j] - mean) * rstd * lnw_v[j] + lnb_v[j];
        }
    }
}

// ---------------------------------------------------------------------------
extern "C" void kernel_launch(void* const* d_in, const int* in_sizes, int n_in,
                              void* d_out, int out_size, void* d_ws, size_t ws_size,
                              hipStream_t stream)
{
    const float* x     = (const float*)d_in[0];
    const float* cheb  = (const float*)d_in[1];
    const float* W1    = (const float*)d_in[2];
    const float* W2    = (const float*)d_in[3];
    const float* W3    = (const float*)d_in[4];
    const float* bs    = (const float*)d_in[5];
    const float* Vs    = (const float*)d_in[6];
    const float* U1    = (const float*)d_in[7];
    const float* U2    = (const float*)d_in[8];
    const float* U3    = (const float*)d_in[9];
    const float* be    = (const float*)d_in[10];
    const float* Ve    = (const float*)d_in[11];
    const float* Theta = (const float*)d_in[12];
    const float* cw    = (const float*)d_in[13];
    const float* cbp   = (const float*)d_in[14];
    const float* lnw   = (const float*)d_in[15];
    const float* lnb   = (const float*)d_in[16];
    float* out = (float*)d_out;
    float* ws  = (float*)d_ws;

    // workspace layout (offsets in f32 slots); peak ~138.5 MB
    // W2g is 12288 u16 = 6144 f32 -> [2115584, 2121728). (R7 bug: ThT at +3072
    // overlapped W2g's upper half.) ThT now OVERLAYS part: ThT's last read
    // (k_xtheta_mfma, half=1) precedes part's first write (k_hU1_part).
    unsigned short* Vs_bf   = (unsigned short*)(ws);              // 131072 f32
    unsigned short* cheb_bf = (unsigned short*)(ws + 131072);     // 393216 f32
    float*  lhs  = ws + 524288;     // 393216 (also lhs_t)
    float*  rhs  = ws + 917504;     // 393216 (also rhs_t)
    float*  part = ws + 1310720;    // 786432
    unsigned short* ThT = (unsigned short*)(ws + 1310720);        // 12288 u16, overlays part
    float*  Ebuf = ws + 2097152;    // 18432
    unsigned short* W2g = (unsigned short*)(ws + 2115584);        // 12288 u16 = 6144 f32
    unsigned short* St  = (unsigned short*)(ws + 2124800);        // 8388608 u16
    unsigned short* Wk  = (unsigned short*)(ws + 6319104);        // 12582912 u16
    unsigned short* XTt = (unsigned short*)(ws + 12610560);       // 37748736 u16 -> ends f32 31484928
    unsigned short* Pt  = (unsigned short*)(ws + 12610560);       // overlay (dead before XTt)
    float*          S0  = ws + 22047744;                          // 8388608 f32 (dead before XTt)
    unsigned short* xT2 = (unsigned short*)(ws + 31484928);       // 6291456 u16 (per half)
    unsigned short* hT  = XTt;                                    // reuse after GEMM loop

    const long long NN2 = (long long)cN * cN;        // 262144
    const long long NFT = (long long)cN * cFT;       // 786432
    const long long segW = 16LL * NN2;               // Wk k-segment (u16 elems)
    const long long segX = 16LL * 1536 * 512;        // XTt k-segment

    k_convert<<<1024, 256, 0, stream>>>(Vs, Vs_bf, 262144);
    k_convert<<<3072, 256, 0, stream>>>(cheb, cheb_bf, 786432);
    k_wprep<<<48, 256, 0, stream>>>(cw, W2g);
    k_thprep<<<48, 256, 0, stream>>>(Theta, ThT);

    // spatial attention
    k_spatial_lr<<<cB * cN, 64, 0, stream>>>(x, W1, W2, W3, lhs, rhs);
    k_product_t<<<dim3(32, 32, cB), dim3(16, 16), 0, stream>>>(lhs, rhs, bs, Pt);
    k_mfma_gemm<0><<<dim3(4, 4, cB), 256, 0, stream>>>(
        Vs_bf, 512, 0LL, 0LL, Pt, 512, NN2, 0LL, S0, 512, NN2, 512, 0, 0);
    k_softmax512<<<cB * cN, 256, 0, stream>>>(S0);
    k_transpose_S<<<dim3(8, 8, cB), 256, 0, stream>>>(S0, St);

    // Cheb conv, batch-halved with fused-K final GEMM
    for (int half = 0; half < 2; half++) {
        k_xtrans_half<<<16 * 512, 64, 0, stream>>>(x, half, xT2);
        k_xtheta_mfma<<<dim3(4, 24, 16), 256, 0, stream>>>(xT2, ThT, XTt, segX);
        for (int k = 0; k < cK; k++) {
            k_mfma_gemm<1><<<dim3(4, 4, 16), 256, 0, stream>>>(
                cheb_bf + (size_t)k * NN2, 512, 0LL, 0LL,
                St + (size_t)half * 16 * NN2, 512, NN2, 0LL,
                Wk + (size_t)k * segW, 512, NN2, 512, 0, 0);
        }
        // h_half = relu( sum_k W_k @ XT_k )  — one pass, K=1536 segmented
        k_mfma_gemm<0><<<dim3(12, 4, 16), 256, 0, stream>>>(
            Wk, 512, NN2, segW, XTt, 512, 786432LL, segX,
            out + (size_t)half * 16 * NFT, 1536, NFT, 1536, 0, 1);
    }

    // temporal attention (reads h = out, pre-mixing; ThT dead from here)
    k_hU1_part<<<dim3(cB, 16), 256, 0, stream>>>(out, U1, part);
    k_rhs_t<<<cB * cN, 64, 0, stream>>>(out, U3, rhs);
    k_lhs_t<<<dim3(cB, 4), 256, 0, stream>>>(part, U2, lhs);
    k_E<<<cB, 576, 0, stream>>>(lhs, rhs, be, Ve, Ebuf);

    // temporal mixing -> hT (bf16, [t,f] layout), then MFMA conv + LN -> out
    k_tmix_t<<<cB * cN, 256, 0, stream>>>(out, Ebuf, hT);
    k_convmfma<<<2048, 256, 0, stream>>>(hT, x, W2g, cbp, lnw, lnb, out);
}

// Round 12
// 637.831 us; speedup vs baseline: 5.0650x; 1.1022x over previous
//
#include <hip/hip_runtime.h>

// Problem constants
constexpr int cB = 32, cN = 512, cC = 64, cT = 24, cK = 3, cF = 64;
constexpr int cCT = cC * cT;   // 1536
constexpr int cFT = cF * cT;   // 1536

typedef __attribute__((ext_vector_type(8))) short s16x8;            // MFMA bf16 frag
typedef __attribute__((ext_vector_type(8))) unsigned short u16x8;   // 16B load/store
typedef __attribute__((ext_vector_type(4))) float f32x4;            // MFMA acc

__device__ inline unsigned short f2bf(float f) {
    union { float f; unsigned int u; } v; v.f = f;
    unsigned int r = v.u + 0x7FFFu + ((v.u >> 16) & 1u);
    return (unsigned short)(r >> 16);
}

// ---------------------------------------------------------------------------
__global__ __launch_bounds__(64) void k_spatial_lr(
    const float* __restrict__ x, const float* __restrict__ W1,
    const float* __restrict__ W2, const float* __restrict__ W3,
    float* __restrict__ lhs, float* __restrict__ rhs)
{
    int bn = blockIdx.x;
    int tid = threadIdx.x;
    __shared__ float xs[64][25];
    __shared__ float a_sh[64];
    const float* xp = x + (size_t)bn * cCT;
    for (int i = tid; i < cCT; i += 64) xs[i / cT][i % cT] = xp[i];
    __syncthreads();
    float s = 0.f;
    #pragma unroll
    for (int t = 0; t < cT; t++) s += xs[tid][t] * W1[t];
    a_sh[tid] = s;
    __syncthreads();
    if (tid < cT) {
        float l = 0.f, r = 0.f;
        for (int c = 0; c < cC; c++) {
            l += a_sh[c] * W2[c * cT + tid];
            r += xs[c][tid] * W3[c];
        }
        lhs[(size_t)bn * cT + tid] = l;
        rhs[(size_t)bn * cT + tid] = r;
    }
}

// ---------------------------------------------------------------------------
// Pt[b,n,m] = bf16(sigmoid(sum_t lhs[b,m,t]*rhs[b,n,t] + bs[m,n]))  (transposed)
__global__ __launch_bounds__(256) void k_product_t(
    const float* __restrict__ lhs, const float* __restrict__ rhs,
    const float* __restrict__ bs, unsigned short* __restrict__ Pt)
{
    int b = blockIdx.z;
    int m0 = blockIdx.y * 16, n0 = blockIdx.x * 16;
    int tx = threadIdx.x, ty = threadIdx.y;
    int tid = ty * 16 + tx;
    __shared__ float L[16][25], R[16][25], bss[16][17];
    for (int i = tid; i < 16 * cT; i += 256) {
        int r = i / cT, c = i % cT;
        L[r][c] = lhs[((size_t)b * cN + m0 + r) * cT + c];
        R[r][c] = rhs[((size_t)b * cN + n0 + r) * cT + c];
    }
    bss[tid >> 4][tid & 15] = bs[(size_t)(m0 + (tid >> 4)) * cN + n0 + (tid & 15)];
    __syncthreads();
    float s = 0.f;
    #pragma unroll
    for (int t = 0; t < cT; t++) s += L[tx][t] * R[ty][t];
    s += bss[tx][ty];
    float sig = 1.f / (1.f + expf(-s));
    Pt[((size_t)b * cN + n0 + ty) * cN + m0 + tx] = f2bf(sig);
}

// ---------------------------------------------------------------------------
// Batched bf16 MFMA GEMM, 128x128 tile, BK=32, 4 waves, 16x16x32 MFMA.
// Segmented K (512 per segment). Pass segA=segB=0 for K<=512.
template<int CM>
__global__ __launch_bounds__(256) void k_mfma_gemm(
    const unsigned short* __restrict__ A, int lda, long long aB, long long segA,
    const unsigned short* __restrict__ Bt, int ldb, long long bB, long long segB,
    void* __restrict__ Cv, int ldc, long long cBs,
    int K, int doAcc, int doRelu)
{
    __shared__ unsigned short As[128][40];
    __shared__ unsigned short Bs[128][40];
    int tid = threadIdx.x;
    int bn = blockIdx.x * 128;
    int bm = blockIdx.y * 128;
    int z  = blockIdx.z;
    const unsigned short* Ap = A  + (size_t)z * aB;
    const unsigned short* Bp = Bt + (size_t)z * bB;

    int lane = tid & 63, w = tid >> 6;
    int wm = (w >> 1) * 64, wn = (w & 1) * 64;
    int fr = lane & 15, kg = (lane >> 4) * 8;

    f32x4 acc[4][4] = {};

    int c0 = tid, c1 = tid + 256;
    int r0 = c0 >> 2, g0 = (c0 & 3) * 8;
    int r1 = c1 >> 2, g1 = (c1 & 3) * 8;

    for (int k0 = 0; k0 < K; k0 += 32) {
        int seg = k0 >> 9, off = k0 & 511;
        const unsigned short* Aseg = Ap + (size_t)seg * segA;
        const unsigned short* Bseg = Bp + (size_t)seg * segB;
        u16x8 a0 = *(const u16x8*)(Aseg + (size_t)(bm + r0) * lda + off + g0);
        u16x8 a1 = *(const u16x8*)(Aseg + (size_t)(bm + r1) * lda + off + g1);
        u16x8 b0 = *(const u16x8*)(Bseg + (size_t)(bn + r0) * ldb + off + g0);
        u16x8 b1 = *(const u16x8*)(Bseg + (size_t)(bn + r1) * ldb + off + g1);
        __syncthreads();
        *(u16x8*)&As[r0][g0] = a0;
        *(u16x8*)&As[r1][g1] = a1;
        *(u16x8*)&Bs[r0][g0] = b0;
        *(u16x8*)&Bs[r1][g1] = b1;
        __syncthreads();
        s16x8 af[4], bf[4];
        #pragma unroll
        for (int i = 0; i < 4; i++)
            af[i] = *(const s16x8*)&As[wm + i * 16 + fr][kg];
        #pragma unroll
        for (int j = 0; j < 4; j++)
            bf[j] = *(const s16x8*)&Bs[wn + j * 16 + fr][kg];
        #pragma unroll
        for (int i = 0; i < 4; i++)
            #pragma unroll
            for (int j = 0; j < 4; j++)
                acc[i][j] = __builtin_amdgcn_mfma_f32_16x16x32_bf16(
                    af[i], bf[j], acc[i][j], 0, 0, 0);
    }
    int rb = (lane >> 4) * 4;
    if (CM == 0) {
        float* Cp = (float*)Cv + (size_t)z * cBs;
        #pragma unroll
        for (int i = 0; i < 4; i++) {
            int row = bm + wm + i * 16 + rb;
            #pragma unroll
            for (int j = 0; j < 4; j++) {
                int col = bn + wn + j * 16 + fr;
                #pragma unroll
                for (int r = 0; r < 4; r++) {
                    size_t idx = (size_t)(row + r) * ldc + col;
                    float v = acc[i][j][r];
                    if (doAcc) v += Cp[idx];
                    if (doRelu) v = fmaxf(v, 0.f);
                    Cp[idx] = v;
                }
            }
        }
    } else {
        unsigned short* Cp = (unsigned short*)Cv + (size_t)z * cBs;
        #pragma unroll
        for (int i = 0; i < 4; i++) {
            int row = bm + wm + i * 16 + rb;
            #pragma unroll
            for (int j = 0; j < 4; j++) {
                int col = bn + wn + j * 16 + fr;
                #pragma unroll
                for (int r = 0; r < 4; r++)
                    Cp[(size_t)(row + r) * ldc + col] = f2bf(acc[i][j][r]);
            }
        }
    }
}

// ---------------------------------------------------------------------------
__global__ __launch_bounds__(256) void k_softmax512(float* __restrict__ S)
{
    int row = blockIdx.x;
    int tid = threadIdx.x;
    float* p = S + (size_t)row * cN;
    float v0 = p[tid], v1 = p[tid + 256];
    __shared__ float red[256];
    red[tid] = fmaxf(v0, v1);
    __syncthreads();
    for (int off = 128; off > 0; off >>= 1) {
        if (tid < off) red[tid] = fmaxf(red[tid], red[tid + off]);
        __syncthreads();
    }
    float mx = red[0];
    __syncthreads();
    float e0 = expf(v0 - mx), e1 = expf(v1 - mx);
    red[tid] = e0 + e1;
    __syncthreads();
    for (int off = 128; off > 0; off >>= 1) {
        if (tid < off) red[tid] += red[tid + off];
        __syncthreads();
    }
    float inv = 1.f / red[0];
    p[tid] = e0 * inv;
    p[tid + 256] = e1 * inv;
}

// ---------------------------------------------------------------------------
__global__ __launch_bounds__(256) void k_transpose_S(
    const float* __restrict__ S0, unsigned short* __restrict__ St)
{
    int b = blockIdx.z;
    int q0 = blockIdx.y * 64, n0 = blockIdx.x * 64;
    __shared__ float t[64][68];
    int tid = threadIdx.x;
    int r = tid >> 2, grp = (tid & 3) * 16;
    const float* ip = S0 + ((size_t)b * cN + q0 + r) * cN + n0 + grp;
    #pragma unroll
    for (int i = 0; i < 16; i += 4)
        *(float4*)&t[r][grp + i] = *(const float4*)(ip + i);
    __syncthreads();
    int nr = tid & 63, qg = (tid >> 6) * 16;
    unsigned short* op = St + ((size_t)b * cN + n0 + nr) * cN + q0 + qg;
    u16x8 v0, v1;
    #pragma unroll
    for (int i = 0; i < 8; i++) {
        v0[i] = f2bf(t[qg + i][nr]);
        v1[i] = f2bf(t[qg + 8 + i][nr]);
    }
    *(u16x8*)op = v0;
    *(u16x8*)(op + 8) = v1;
}

// ---------------------------------------------------------------------------
// xT2[z][t][n][c] = bf16(x[half*16+z][n][c][t])   (one pass per half)
__global__ __launch_bounds__(64) void k_xtrans_half(
    const float* __restrict__ x, int half, unsigned short* __restrict__ xT2)
{
    int idx = blockIdx.x;            // z*512 + n
    int z = idx >> 9, n = idx & 511;
    int b = half * 16 + z;
    int tid = threadIdx.x;
    __shared__ float xs[64][25];
    const float* xp = x + (size_t)(b * (size_t)cN + n) * cCT;
    for (int i = tid; i < cCT; i += 64) xs[i / cT][i % cT] = xp[i];
    __syncthreads();
    unsigned short* op = xT2 + (size_t)z * 786432 + (size_t)n * 64;
    for (int i = tid; i < cCT; i += 64) {
        int t = i >> 6, c = i & 63;
        op[(size_t)t * 32768 + c] = f2bf(xs[c][t]);
    }
}

// ---------------------------------------------------------------------------
// XT via MFMA, direct write to XTt[k][z][f*24+t][n].
__global__ __launch_bounds__(256) void k_xtheta_mfma(
    const unsigned short* __restrict__ xT2,   // [z][t][n][c]
    const unsigned short* __restrict__ ThT,   // [k][f][c]
    unsigned short* __restrict__ XTt,         // [k][z][f*24+t][n]
    long long segX)
{
    __shared__ unsigned short As[128][72];
    __shared__ unsigned short Ths[64][72];
    __shared__ unsigned short Cs[64][136];
    int tid = threadIdx.x;
    int n0 = blockIdx.x * 128;
    int t  = blockIdx.y;
    int z  = blockIdx.z;

    const unsigned short* ap = xT2 + (size_t)z * 786432 + (size_t)t * 32768 + n0 * 64;
    #pragma unroll
    for (int it = 0; it < 4; it++) {
        int v = tid + it * 256;
        int row = v >> 3, c8 = (v & 7) * 8;
        *(u16x8*)&As[row][c8] = *(const u16x8*)(ap + row * 64 + c8);
    }

    int lane = tid & 63, w = tid >> 6;
    int fr = lane & 15, kg = (lane >> 4) * 8;
    int rb = (lane >> 4) * 4;

    for (int k = 0; k < cK; k++) {
        __syncthreads();   // prev Cs/Ths reads + (k=0) A-stage done
        #pragma unroll
        for (int it = 0; it < 2; it++) {
            int vi = tid + it * 256;         // 0..511
            int row = vi >> 3, c8 = (vi & 7) * 8;
            *(u16x8*)&Ths[row][c8] =
                *(const u16x8*)(ThT + (size_t)k * 4096 + row * 64 + c8);
        }
        __syncthreads();
        f32x4 acc[2][4] = {};
        #pragma unroll
        for (int ks = 0; ks < 2; ks++) {
            s16x8 af[2], bf[4];
            #pragma unroll
            for (int i = 0; i < 2; i++)
                af[i] = *(const s16x8*)&As[w * 32 + i * 16 + fr][ks * 32 + kg];
            #pragma unroll
            for (int j = 0; j < 4; j++)
                bf[j] = *(const s16x8*)&Ths[j * 16 + fr][ks * 32 + kg];
            #pragma unroll
            for (int i = 0; i < 2; i++)
                #pragma unroll
                for (int j = 0; j < 4; j++)
                    acc[i][j] = __builtin_amdgcn_mfma_f32_16x16x32_bf16(
                        af[i], bf[j], acc[i][j], 0, 0, 0);
        }
        #pragma unroll
        for (int i = 0; i < 2; i++) {
            int rowb = w * 32 + i * 16 + rb;
            #pragma unroll
            for (int j = 0; j < 4; j++) {
                int f = j * 16 + fr;
                #pragma unroll
                for (int r = 0; r < 4; r++)
                    Cs[f][rowb + r] = f2bf(acc[i][j][r]);
            }
        }
        __syncthreads();
        unsigned short* op = XTt + (size_t)k * segX + (size_t)z * 786432 + n0;
        #pragma unroll
        for (int it = 0; it < 4; it++) {
            int v = tid + it * 256;
            int f = v >> 4, n8 = (v & 15) * 8;
            *(u16x8*)(op + (size_t)(f * 24 + t) * 512 + n8) = *(const u16x8*)&Cs[f][n8];
        }
    }
}

// ---------------------------------------------------------------------------
__global__ void k_convert(const float* __restrict__ a,
                          unsigned short* __restrict__ o, int n)
{
    int i = blockIdx.x * 256 + threadIdx.x;
    if (i < n) o[i] = f2bf(a[i]);
}

// ---------------------------------------------------------------------------
// W2g[f][d*64+fi] = bf16(conv_w[f][fi][0][d])
__global__ void k_wprep(const float* __restrict__ cw,
                        unsigned short* __restrict__ W2g)
{
    int i = blockIdx.x * 256 + threadIdx.x;
    if (i < 64 * 192) {
        int f = i / 192, k = i % 192;
        int d = k >> 6, fi = k & 63;
        W2g[i] = f2bf(cw[f * 192 + fi * 3 + d]);
    }
}

// ---------------------------------------------------------------------------
// ThT[k][f][c] = bf16(Theta[k][c][f])
__global__ void k_thprep(const float* __restrict__ Theta,
                         unsigned short* __restrict__ ThT)
{
    int i = blockIdx.x * 256 + threadIdx.x;
    if (i < cK * 64 * 64) {
        int k = i >> 12, r = i & 4095;
        int f = r >> 6, c = r & 63;
        ThT[i] = f2bf(Theta[k * 4096 + c * 64 + f]);
    }
}

// ---------------------------------------------------------------------------
__global__ __launch_bounds__(256) void k_hU1_part(
    const float* __restrict__ h, const float* __restrict__ U1,
    float* __restrict__ part)
{
    int b = blockIdx.x, nc = blockIdx.y;
    int tid = threadIdx.x;
    int f = tid & 63, q = tid >> 6;
    float acc[24];
    #pragma unroll
    for (int t = 0; t < 24; t++) acc[t] = 0.f;
    for (int n = nc * 32 + q; n < nc * 32 + 32; n += 4) {
        float u = U1[n];
        const float4* hp = (const float4*)(h + (((size_t)b * cN + n) * cF + f) * cT);
        #pragma unroll
        for (int v4 = 0; v4 < 6; v4++) {
            float4 hv = hp[v4];
            acc[v4 * 4 + 0] += u * hv.x;
            acc[v4 * 4 + 1] += u * hv.y;
            acc[v4 * 4 + 2] += u * hv.z;
            acc[v4 * 4 + 3] += u * hv.w;
        }
    }
    __shared__ float ps[4][64][25];
    #pragma unroll
    for (int t = 0; t < 24; t++) ps[q][f][t] = acc[t];
    __syncthreads();
    for (int i = tid; i < cFT; i += 256) {
        int f2 = i / cT, t2 = i % cT;
        float s = ps[0][f2][t2] + ps[1][f2][t2] + ps[2][f2][t2] + ps[3][f2][t2];
        part[(((size_t)b * 16 + nc) * cF + f2) * cT + t2] = s;
    }
}

// ---------------------------------------------------------------------------
__global__ __launch_bounds__(256) void k_lhs_t(
    const float* __restrict__ part, const float* __restrict__ U2,
    float* __restrict__ lhs_t)
{
    int b = blockIdx.x, ch = blockIdx.y;
    int tid = threadIdx.x;
    __shared__ float hu[1536];
    for (int i = tid; i < 1536; i += 256) {
        float s = 0.f;
        for (int nc = 0; nc < 16; nc++)
            s += part[((size_t)b * 16 + nc) * 1536 + i];
        hu[i] = s;
    }
    __syncthreads();
    int nn0 = ch * 128;
    for (int i = tid; i < cT * 128; i += 256) {
        int t = i / 128, nn = nn0 + (i % 128);
        float s = 0.f;
        #pragma unroll
        for (int f = 0; f < 64; f++) s += hu[f * cT + t] * U2[(size_t)f * cN + nn];
        lhs_t[((size_t)b * cT + t) * cN + nn] = s;
    }
}

// ---------------------------------------------------------------------------
__global__ __launch_bounds__(64) void k_rhs_t(
    const float* __restrict__ h, const float* __restrict__ U3,
    float* __restrict__ rhs_t)
{
    int bn = blockIdx.x;
    int f = threadIdx.x;
    __shared__ float sl[64][25];
    const float4* hp = (const float4*)(h + (size_t)bn * cFT + f * cT);
    float u = U3[f];
    #pragma unroll
    for (int v4 = 0; v4 < 6; v4++) {
        float4 hv = hp[v4];
        sl[f][v4 * 4 + 0] = u * hv.x;
        sl[f][v4 * 4 + 1] = u * hv.y;
        sl[f][v4 * 4 + 2] = u * hv.z;
        sl[f][v4 * 4 + 3] = u * hv.w;
    }
    __syncthreads();
    if (f < cT) {
        float s = 0.f;
        #pragma unroll
        for (int c = 0; c < 64; c++) s += sl[c][f];
        rhs_t[(size_t)bn * cT + f] = s;
    }
}

// ---------------------------------------------------------------------------
__global__ __launch_bounds__(576) void k_E(
    const float* __restrict__ lhs_t, const float* __restrict__ rhs_t,
    const float* __restrict__ be, const float* __restrict__ Ve,
    float* __restrict__ E)
{
    int b = blockIdx.x;
    int tid = threadIdx.x;
    int i = tid / 24, j = tid % 24;
    __shared__ float ps[24][25];
    __shared__ float er[24][25];
    __shared__ float mrow[24], srow[24];
    const float* lp = lhs_t + ((size_t)b * cT + i) * cN;
    const float* rp = rhs_t + (size_t)b * cN * cT;
    float s = 0.f;
    for (int n = 0; n < cN; n++) s += lp[n] * rp[n * cT + j];
    s += be[i * cT + j];
    ps[i][j] = 1.f / (1.f + expf(-s));
    __syncthreads();
    float e = 0.f;
    #pragma unroll
    for (int ss = 0; ss < cT; ss++) e += Ve[i * cT + ss] * ps[ss][j];
    er[i][j] = e;
    __syncthreads();
    if (j == 0) {
        float m = -1e30f;
        for (int r = 0; r < cT; r++) m = fmaxf(m, er[i][r]);
        float sm = 0.f;
        for (int r = 0; r < cT; r++) sm += expf(er[i][r] - m);
        mrow[i] = m;
        srow[i] = sm;
    }
    __syncthreads();
    E[(size_t)b * cT * cT + i * cT + j] = expf(er[i][j] - mrow[i]) / srow[i];
}

// ---------------------------------------------------------------------------
// temporal mixing, emits hT[b,n,t,f] in bf16 (h input unchanged)
__global__ __launch_bounds__(256) void k_tmix_t(
    const float* __restrict__ h, const float* __restrict__ E,
    unsigned short* __restrict__ hT)
{
    int bn = blockIdx.x;
    int b = bn >> 9;
    int tid = threadIdx.x;
    __shared__ float hs[64][25];
    __shared__ float Es[24][24];
    __shared__ float outs[24][65];
    const float4* hp = (const float4*)(h + (size_t)bn * cFT);
    // 1536 f32 = 384 vec4; 24 = 6*4 so each vec4 stays in one f-row
    for (int i = tid; i < 384; i += 256) {
        float4 v = hp[i];
        int f = i / 6, t0 = (i % 6) * 4;
        hs[f][t0] = v.x; hs[f][t0 + 1] = v.y;
        hs[f][t0 + 2] = v.z; hs[f][t0 + 3] = v.w;
    }
    for (int i = tid; i < 576; i += 256)
        Es[i / 24][i % 24] = E[(size_t)b * 576 + i];
    __syncthreads();
    int f = tid & 63, g = tid >> 6;
    #pragma unroll
    for (int j = 0; j < 6; j++) {
        int so = g * 6 + j;
        float s = 0.f;
        #pragma unroll
        for (int t = 0; t < cT; t++) s += hs[f][t] * Es[t][so];
        outs[so][f] = s;
    }
    __syncthreads();
    unsigned short* op = hT + (size_t)bn * cFT;
    for (int i = tid; i < cFT; i += 256)
        op[i] = f2bf(outs[i >> 6][i & 63]);
}

// ---------------------------------------------------------------------------
// MFMA conv(1,3) + bias + residual(x) + LayerNorm over F. float4 stores.
__global__ __launch_bounds__(256) void k_convmfma(
    const unsigned short* __restrict__ hT,   // [b,n,t,f] bf16
    const float* __restrict__ x,             // [b,n,c,t] f32
    const unsigned short* __restrict__ W2g,  // [f][192] bf16, k=(d*64+fi)
    const float* __restrict__ cb,
    const float* __restrict__ lnw, const float* __restrict__ lnb,
    float* __restrict__ out)                 // [b,n,f,t] f32
{
    __shared__ unsigned short Hs[8][26][72];
    __shared__ unsigned short Ws[64][200];
    int tid = threadIdx.x;
    int blk = blockIdx.x;
    int b = blk >> 6;
    int n0 = (blk & 63) * 8;
    const unsigned short* hp = hT + ((size_t)b * cN + n0) * cFT;

    #pragma unroll
    for (int it = 0; it < 6; it++) {
        int v = tid + it * 256;
        int s = v / 192;
        int r = v % 192;
        int t = r >> 3, f0 = (r & 7) * 8;
        u16x8 val = *(const u16x8*)(hp + (size_t)s * cFT + t * 64 + f0);
        *(u16x8*)&Hs[s][1 + t][f0] = val;
    }
    if (tid < 144) {
        int s = tid / 18, rm = tid % 18;
        int side = rm / 9, c8 = (rm % 9) * 8;
        u16x8 z = {};
        *(u16x8*)&Hs[s][side * 25][c8] = z;
    }
    #pragma unroll
    for (int it = 0; it < 48; it++) {
        int i = tid + it * 256;
        Ws[i / 192][i % 192] = W2g[i];
    }
    __syncthreads();

    int lane = tid & 63, w = tid >> 6;
    int fr = lane & 15, kgrp = lane >> 4;
    f32x4 acc[3][4] = {};

    int sA[3], tA[3];
    #pragma unroll
    for (int mi = 0; mi < 3; mi++) {
        int row = (w * 3 + mi) * 16 + fr;
        sA[mi] = row / 24; tA[mi] = row % 24;
    }
    #pragma unroll
    for (int ks = 0; ks < 6; ks++) {
        int d = ks >> 1;
        int fi0 = (ks & 1) * 32 + kgrp * 8;
        s16x8 bf[4];
        #pragma unroll
        for (int j = 0; j < 4; j++)
            bf[j] = *(const s16x8*)&Ws[j * 16 + fr][ks * 32 + kgrp * 8];
        #pragma unroll
        for (int mi = 0; mi < 3; mi++) {
            s16x8 af = *(const s16x8*)&Hs[sA[mi]][tA[mi] + d][fi0];
            #pragma unroll
            for (int j = 0; j < 4; j++)
                acc[mi][j] = __builtin_amdgcn_mfma_f32_16x16x32_bf16(
                    af, bf[j], acc[mi][j], 0, 0, 0);
        }
    }

    float lnw_v[4], lnb_v[4], cb_v[4];
    #pragma unroll
    for (int j = 0; j < 4; j++) {
        int f = j * 16 + fr;
        lnw_v[j] = lnw[f]; lnb_v[j] = lnb[f]; cb_v[j] = cb[f];
    }
    #pragma unroll
    for (int mi = 0; mi < 3; mi++) {
        int rowbase = (w * 3 + mi) * 16 + kgrp * 4;
        // rowbase % 4 == 0 and 24 % 4 == 0 => all 4 r share one slab s, t = tb + r
        int sB = rowbase / 24, tb = rowbase % 24;
        size_t slab = ((size_t)b * cN + n0 + sB) * 64;
        float outv[4][4];   // [j][r]
        #pragma unroll
        for (int r = 0; r < 4; r++) {
            int t = tb + r;
            float v[4], s1 = 0.f, s2 = 0.f;
            #pragma unroll
            for (int j = 0; j < 4; j++) {
                float xres = x[(slab + j * 16 + fr) * 24 + t];
                v[j] = acc[mi][j][r] + cb_v[j] + xres;
                s1 += v[j];
                s2 += v[j] * v[j];
            }
            #pragma unroll
            for (int off = 1; off < 16; off <<= 1) {
                s1 += __shfl_xor(s1, off, 64);
                s2 += __shfl_xor(s2, off, 64);
            }
            float mean = s1 * (1.f / 64.f);
            float var = s2 * (1.f / 64.f) - mean * mean;
            float rstd = rsqrtf(var + 1e-5f);
            #pragma unroll
            for (int j = 0; j < 4; j++)
                outv[j][r] = (v[j] - mean) * rstd * lnw_v[j] + lnb_v[j];
        }
        #pragma unroll
        for (int j = 0; j < 4; j++) {
            float4 o = make_float4(outv[j][0], outv[j][1], outv[j][2], outv[j][3]);
            *(float4*)&out[(slab + j * 16 + fr) * 24 + tb] = o;
        }
    }
}

// ---------------------------------------------------------------------------
extern "C" void kernel_launch(void* const* d_in, const int* in_sizes, int n_in,
                              void* d_out, int out_size, void* d_ws, size_t ws_size,
                              hipStream_t stream)
{
    const float* x     = (const float*)d_in[0];
    const float* cheb  = (const float*)d_in[1];
    const float* W1    = (const float*)d_in[2];
    const float* W2    = (const float*)d_in[3];
    const float* W3    = (const float*)d_in[4];
    const float* bs    = (const float*)d_in[5];
    const float* Vs    = (const float*)d_in[6];
    const float* U1    = (const float*)d_in[7];
    const float* U2    = (const float*)d_in[8];
    const float* U3    = (const float*)d_in[9];
    const float* be    = (const float*)d_in[10];
    const float* Ve    = (const float*)d_in[11];
    const float* Theta = (const float*)d_in[12];
    const float* cw    = (const float*)d_in[13];
    const float* cbp   = (const float*)d_in[14];
    const float* lnw   = (const float*)d_in[15];
    const float* lnb   = (const float*)d_in[16];
    float* out = (float*)d_out;
    float* ws  = (float*)d_ws;

    // workspace layout: exactly the round-8 PASSING layout (peak 138.5 MB).
    unsigned short* Vs_bf   = (unsigned short*)(ws);              // 131072 f32
    unsigned short* cheb_bf = (unsigned short*)(ws + 131072);     // 393216 f32
    float*  lhs  = ws + 524288;     // 393216 (also lhs_t)
    float*  rhs  = ws + 917504;     // 393216 (also rhs_t)
    float*  part = ws + 1310720;    // 786432
    unsigned short* ThT = (unsigned short*)(ws + 1310720);        // overlays part (dead before part's first write)
    float*  Ebuf = ws + 2097152;    // 18432
    unsigned short* W2g = (unsigned short*)(ws + 2115584);        // 12288 u16 = 6144 f32
    unsigned short* St  = (unsigned short*)(ws + 2124800);        // 8388608 u16
    unsigned short* Wk  = (unsigned short*)(ws + 6319104);        // 12582912 u16
    unsigned short* XTt = (unsigned short*)(ws + 12610560);       // 37748736 u16 -> ends f32 31484928
    unsigned short* Pt  = (unsigned short*)(ws + 12610560);       // overlay (dead before XTt)
    float*          S0  = ws + 22047744;                          // 8388608 f32 (dead before XTt)
    unsigned short* xT2 = (unsigned short*)(ws + 31484928);       // 6291456 u16 (per half)
    unsigned short* hT  = XTt;                                    // reuse after GEMM loop

    const long long NN2 = (long long)cN * cN;        // 262144
    const long long NFT = (long long)cN * cFT;       // 786432
    const long long segW = 16LL * NN2;               // Wk k-segment (u16 elems)
    const long long segX = 16LL * 1536 * 512;        // XTt k-segment

    k_convert<<<1024, 256, 0, stream>>>(Vs, Vs_bf, 262144);
    k_convert<<<3072, 256, 0, stream>>>(cheb, cheb_bf, 786432);
    k_wprep<<<48, 256, 0, stream>>>(cw, W2g);
    k_thprep<<<48, 256, 0, stream>>>(Theta, ThT);

    // spatial attention
    k_spatial_lr<<<cB * cN, 64, 0, stream>>>(x, W1, W2, W3, lhs, rhs);
    k_product_t<<<dim3(32, 32, cB), dim3(16, 16), 0, stream>>>(lhs, rhs, bs, Pt);
    k_mfma_gemm<0><<<dim3(4, 4, cB), 256, 0, stream>>>(
        Vs_bf, 512, 0LL, 0LL, Pt, 512, NN2, 0LL, S0, 512, NN2, 512, 0, 0);
    k_softmax512<<<cB * cN, 256, 0, stream>>>(S0);
    k_transpose_S<<<dim3(8, 8, cB), 256, 0, stream>>>(S0, St);

    // Cheb conv, batch-halved with fused-K final GEMM -> h (f32, relu) in d_out
    for (int half = 0; half < 2; half++) {
        k_xtrans_half<<<16 * 512, 64, 0, stream>>>(x, half, xT2);
        k_xtheta_mfma<<<dim3(4, 24, 16), 256, 0, stream>>>(xT2, ThT, XTt, segX);
        for (int k = 0; k < cK; k++) {
            k_mfma_gemm<1><<<dim3(4, 4, 16), 256, 0, stream>>>(
                cheb_bf + (size_t)k * NN2, 512, 0LL, 0LL,
                St + (size_t)half * 16 * NN2, 512, NN2, 0LL,
                Wk + (size_t)k * segW, 512, NN2, 512, 0, 0);
        }
        k_mfma_gemm<0><<<dim3(12, 4, 16), 256, 0, stream>>>(
            Wk, 512, NN2, segW, XTt, 512, 786432LL, segX,
            out + (size_t)half * 16 * NFT, 1536, NFT, 1536, 0, 1);
    }

    // temporal attention (reads h = out f32; ThT dead from here)
    k_hU1_part<<<dim3(cB, 16), 256, 0, stream>>>(out, U1, part);
    k_rhs_t<<<cB * cN, 64, 0, stream>>>(out, U3, rhs);
    k_lhs_t<<<dim3(cB, 4), 256, 0, stream>>>(part, U2, lhs);
    k_E<<<cB, 576, 0, stream>>>(lhs, rhs, be, Ve, Ebuf);

    // temporal mixing -> hT (bf16, [t,f] layout), then MFMA conv + LN -> out
    k_tmix_t<<<cB * cN, 256, 0, stream>>>(out, Ebuf, hT);
    k_convmfma<<<2048, 256, 0, stream>>>(hT, x, W2g, cbp, lnw, lnb, out);
}